// Round 2
// baseline (3529.683 us; speedup 1.0000x reference)
//
#include <hip/hip_runtime.h>
#include <hip/hip_bf16.h>

#define NN 131072
#define EE 2097152
#define EPSS 1e-5f

static __device__ __forceinline__ ushort f2bf(float f) {
    uint u = __float_as_uint(f);
    u += 0x7fffu + ((u >> 16) & 1u);
    return (ushort)(u >> 16);
}
static __device__ __forceinline__ float bf2f(ushort h) {
    return __uint_as_float(((uint)h) << 16);
}

// ---------------- debug: leak ws_size through d_out if workspace too small ----------------

__global__ void dbg_kernel(float* __restrict__ out, float a, float b) {
    int i = threadIdx.x;
    if (i < 80) out[i] = (i == 0) ? a : ((i == 1) ? b : 0.f);
}

// ---------------- CSR build ----------------

__global__ void hist_kernel(const int* __restrict__ dst, int* __restrict__ deg) {
    int e = blockIdx.x * 256 + threadIdx.x;
    if (e < EE) atomicAdd(&deg[dst[e]], 1);
}

__global__ __launch_bounds__(1024) void scanA_kernel(const int* __restrict__ deg,
                                                     int* __restrict__ rp,
                                                     int* __restrict__ bsum) {
    __shared__ int sh[1024];
    int t = threadIdx.x;
    int base = blockIdx.x * 1024;
    int v = deg[base + t];
    sh[t] = v;
    __syncthreads();
    for (int off = 1; off < 1024; off <<= 1) {
        int x = (t >= off) ? sh[t - off] : 0;
        __syncthreads();
        sh[t] += x;
        __syncthreads();
    }
    rp[base + t + 1] = sh[t];
    if (t == 1023) bsum[blockIdx.x] = sh[t];
}

__global__ __launch_bounds__(128) void scanB_kernel(int* __restrict__ bsum, int* __restrict__ boff) {
    __shared__ int sh[128];
    int t = threadIdx.x;
    int v = bsum[t];
    sh[t] = v;
    __syncthreads();
    for (int off = 1; off < 128; off <<= 1) {
        int x = (t >= off) ? sh[t - off] : 0;
        __syncthreads();
        sh[t] += x;
        __syncthreads();
    }
    boff[t] = sh[t] - v;  // exclusive
}

__global__ __launch_bounds__(1024) void scanC_kernel(int* __restrict__ rp, const int* __restrict__ boff) {
    int t = threadIdx.x;
    int b = blockIdx.x;
    rp[b * 1024 + t + 1] += boff[b];
    if (b == 0 && t == 0) rp[0] = 0;
}

__global__ void scatter_kernel(const int* __restrict__ src, const int* __restrict__ dst,
                               const float* __restrict__ ew, int* __restrict__ cur,
                               int* __restrict__ csrc, float* __restrict__ cw) {
    int e = blockIdx.x * 256 + threadIdx.x;
    if (e < EE) {
        int n = dst[e];
        int p = atomicAdd(&cur[n], 1);
        csrc[p] = src[e];
        cw[p]   = ew[e];
    }
}

// ---------------- conv weight transpose: wT[(c*3+k)*16384 + i*128 + o] ----------------

__global__ void prepw_kernel(const float* __restrict__ w1, const float* __restrict__ w2,
                             const float* __restrict__ w3, float* __restrict__ wT) {
    int idx = blockIdx.x * 256 + threadIdx.x;
    if (idx >= 3 * 3 * 128 * 128) return;
    int o = idx & 127;
    int i = (idx >> 7) & 127;
    int ck = idx >> 14;       // c*3+k
    int k = ck % 3;
    int c = ck / 3;
    const float* w = (c == 0) ? w1 : ((c == 1) ? w2 : w3);
    wT[idx] = w[o * 384 + i * 3 + k];
}

// ---------------- fused dilated convs + combine + BN stats ----------------

__global__ __launch_bounds__(256) void conv_kernel(const float* __restrict__ h,
                                                   const float* __restrict__ wT,
                                                   const float* __restrict__ b1,
                                                   const float* __restrict__ b2,
                                                   const float* __restrict__ b3,
                                                   float* __restrict__ o1,
                                                   float* __restrict__ o2,
                                                   float* __restrict__ o3,
                                                   float* __restrict__ stats) {
    __shared__ float xs[38 * 128];
    int t = threadIdx.x;
    int n0 = blockIdx.x * 32;

    for (int idx4 = t; idx4 < 38 * 32; idx4 += 256) {
        int row = idx4 >> 5, c4 = idx4 & 31;
        int gn = n0 - 3 + row;
        float4 v = make_float4(0.f, 0.f, 0.f, 0.f);
        if (gn >= 0 && gn < NN) v = *(const float4*)&h[(size_t)gn * 128 + c4 * 4];
        *(float4*)&xs[row * 128 + c4 * 4] = v;
    }
    __syncthreads();

    int o = t & 127, half = t >> 7;
    int ln0 = half * 16;

    float acc1[16], acc2[16], acc3[16];
#pragma unroll
    for (int j = 0; j < 16; j++) { acc1[j] = 0.f; acc2[j] = 0.f; acc3[j] = 0.f; }

    for (int i = 0; i < 128; i++) {
        const float* wp = wT + (i << 7) + o;
        float w10 = wp[0 * 16384], w11 = wp[1 * 16384], w12 = wp[2 * 16384];
        float w20 = wp[3 * 16384], w21 = wp[4 * 16384], w22 = wp[5 * 16384];
        float w30 = wp[6 * 16384], w31 = wp[7 * 16384], w32 = wp[8 * 16384];

        float buf[8];
#pragma unroll
        for (int p = 0; p < 6; p++) buf[p] = xs[(ln0 + p) * 128 + i];
#pragma unroll
        for (int j = 0; j < 16; j++) {
            buf[(j + 6) & 7] = xs[(ln0 + j + 6) * 128 + i];
            float xm3 = buf[(j + 0) & 7];
            float xm2 = buf[(j + 1) & 7];
            float xm1 = buf[(j + 2) & 7];
            float x0  = buf[(j + 3) & 7];
            float xp1 = buf[(j + 4) & 7];
            float xp2 = buf[(j + 5) & 7];
            float xp3 = buf[(j + 6) & 7];
            acc1[j] = fmaf(w10, xm1, fmaf(w11, x0, fmaf(w12, xp1, acc1[j])));
            acc2[j] = fmaf(w20, xm2, fmaf(w21, x0, fmaf(w22, xp2, acc2[j])));
            acc3[j] = fmaf(w30, xm3, fmaf(w31, x0, fmaf(w32, xp3, acc3[j])));
        }
    }

    float bb1 = b1[o], bb2 = b2[o], bb3 = b3[o];
    float s1 = 0.f, ss1 = 0.f, s2 = 0.f, ss2 = 0.f, s3 = 0.f, ss3 = 0.f;
#pragma unroll
    for (int j = 0; j < 16; j++) {
        int n = n0 + ln0 + j;
        float c1 = acc1[j] + bb1;
        float c2 = acc2[j] + bb2;
        float c3 = acc3[j] + bb3;
        float t1 = fmaxf(c1, 0.f) + c2;
        float t2 = fmaxf(c2, 0.f) + c3;
        float t3 = fmaxf(c3, 0.f) + c1;
        size_t base = (size_t)n * 128 + o;
        o1[base] = t1; o2[base] = t2; o3[base] = t3;
        s1 += t1; ss1 += t1 * t1;
        s2 += t2; ss2 += t2 * t2;
        s3 += t3; ss3 += t3 * t3;
    }

    __syncthreads();
    float* red = xs;
    red[0 * 256 + t] = s1; red[1 * 256 + t] = ss1;
    red[2 * 256 + t] = s2; red[3 * 256 + t] = ss2;
    red[4 * 256 + t] = s3; red[5 * 256 + t] = ss3;
    __syncthreads();
    if (t < 128) {
#pragma unroll
        for (int p = 0; p < 6; p++)
            atomicAdd(&stats[p * 128 + t], red[p * 256 + t] + red[p * 256 + t + 128]);
    }
}

// ---------------- BN finalize ----------------

__global__ __launch_bounds__(128) void bnfin_kernel(const float* __restrict__ stats,
                                                    const float* __restrict__ g,
                                                    const float* __restrict__ b,
                                                    float* __restrict__ scsh, int q0, int nq) {
    int d = threadIdx.x;
    for (int q = q0; q < q0 + nq; ++q) {
        float s  = stats[(2 * q) * 128 + d];
        float ss = stats[(2 * q + 1) * 128 + d];
        float mu  = s * (1.f / NN);
        float var = ss * (1.f / NN) - mu * mu;
        float sc = g[d] / sqrtf(var + EPSS);
        float sh = b[d] - mu * sc;
        scsh[q * 256 + d] = sc;
        scsh[q * 256 + 128 + d] = sh;
    }
}

// ---------------- fused gconv: CSR gather-aggregate (+BN affine) + GEMM + bias + relu ----
// block = 64 dst nodes, 256 threads. Phase 1: wave w aggregates nodes [w*16, w*16+16)
// (lane = 2 features) into LDS aggs[64][128]. Phase 2: GEMM y = relu(aggs @ W + b).

template<bool INBF, bool OUTBF>
__global__ __launch_bounds__(256) void gconv_kernel(const void* __restrict__ xv,
                                                    const int* __restrict__ rp,
                                                    const int* __restrict__ csrc,
                                                    const float* __restrict__ cw,
                                                    const float* __restrict__ scsh,
                                                    const float* __restrict__ W,
                                                    const float* __restrict__ bias,
                                                    void* __restrict__ yv) {
    __shared__ float aggs[64 * 128];
    __shared__ float WC[32 * 128];
    int t = threadIdx.x;
    int n0 = blockIdx.x * 64;
    int wv = t >> 6, lane = t & 63;
    const float*  xf = (const float*)xv;
    const ushort* xb = (const ushort*)xv;

    float scx = 1.f, scy = 1.f, shx = 0.f, shy = 0.f;
    if (scsh) {
        float2 sc = *(const float2*)&scsh[lane * 2];
        float2 sh = *(const float2*)&scsh[128 + lane * 2];
        scx = sc.x; scy = sc.y; shx = sh.x; shy = sh.y;
    }

    for (int k = 0; k < 16; k++) {
        int n = n0 + wv * 16 + k;
        int beg = rp[n], end = rp[n + 1];
        float ax = 0.f, ay = 0.f, sw = 0.f;
        int e = beg;
        for (; e + 2 <= end; e += 2) {
            int s0 = csrc[e], s1 = csrc[e + 1];
            float w0 = cw[e], w1 = cw[e + 1];
            float v0x, v0y, v1x, v1y;
            if constexpr (INBF) {
                uint u0 = *(const uint*)&xb[(size_t)s0 * 128 + lane * 2];
                uint u1 = *(const uint*)&xb[(size_t)s1 * 128 + lane * 2];
                v0x = __uint_as_float(u0 << 16); v0y = __uint_as_float(u0 & 0xffff0000u);
                v1x = __uint_as_float(u1 << 16); v1y = __uint_as_float(u1 & 0xffff0000u);
            } else {
                float2 v0 = *(const float2*)&xf[(size_t)s0 * 128 + lane * 2];
                float2 v1 = *(const float2*)&xf[(size_t)s1 * 128 + lane * 2];
                v0x = v0.x; v0y = v0.y; v1x = v1.x; v1y = v1.y;
            }
            ax = fmaf(w0, v0x, ax); ay = fmaf(w0, v0y, ay);
            ax = fmaf(w1, v1x, ax); ay = fmaf(w1, v1y, ay);
            sw += w0 + w1;
        }
        if (e < end) {
            int s0 = csrc[e];
            float w0 = cw[e];
            float vx, vy;
            if constexpr (INBF) {
                uint u0 = *(const uint*)&xb[(size_t)s0 * 128 + lane * 2];
                vx = __uint_as_float(u0 << 16); vy = __uint_as_float(u0 & 0xffff0000u);
            } else {
                float2 v0 = *(const float2*)&xf[(size_t)s0 * 128 + lane * 2];
                vx = v0.x; vy = v0.y;
            }
            ax = fmaf(w0, vx, ax); ay = fmaf(w0, vy, ay);
            sw += w0;
        }
        if (scsh) {
            ax = fmaf(sw, shx, ax * scx);
            ay = fmaf(sw, shy, ay * scy);
        }
        aggs[(wv * 16 + k) * 128 + lane * 2]     = ax;
        aggs[(wv * 16 + k) * 128 + lane * 2 + 1] = ay;
    }
    __syncthreads();

    int tx = t & 31, ty = t >> 5;
    float acc[8][4];
#pragma unroll
    for (int j = 0; j < 8; j++)
#pragma unroll
        for (int q = 0; q < 4; q++) acc[j][q] = 0.f;

    for (int ic = 0; ic < 128; ic += 32) {
#pragma unroll
        for (int rep = 0; rep < 4; rep++) {
            int idx = rep * 256 + t;
            int i = idx >> 5, o4 = idx & 31;
            *(float4*)&WC[i * 128 + o4 * 4] = *(const float4*)&W[(size_t)(ic + i) * 128 + o4 * 4];
        }
        __syncthreads();
#pragma unroll
        for (int i = 0; i < 32; i++) {
            float4 w = *(float4*)&WC[i * 128 + tx * 4];
#pragma unroll
            for (int j = 0; j < 8; j++) {
                float a = aggs[(ty * 8 + j) * 128 + ic + i];
                acc[j][0] = fmaf(a, w.x, acc[j][0]);
                acc[j][1] = fmaf(a, w.y, acc[j][1]);
                acc[j][2] = fmaf(a, w.z, acc[j][2]);
                acc[j][3] = fmaf(a, w.w, acc[j][3]);
            }
        }
        __syncthreads();
    }

    float4 bv = *(const float4*)&bias[tx * 4];
#pragma unroll
    for (int j = 0; j < 8; j++) {
        float r0 = fmaxf(acc[j][0] + bv.x, 0.f);
        float r1 = fmaxf(acc[j][1] + bv.y, 0.f);
        float r2 = fmaxf(acc[j][2] + bv.z, 0.f);
        float r3 = fmaxf(acc[j][3] + bv.w, 0.f);
        int n = n0 + ty * 8 + j;
        if constexpr (OUTBF) {
            ushort4 pk;
            pk.x = f2bf(r0); pk.y = f2bf(r1); pk.z = f2bf(r2); pk.w = f2bf(r3);
            *(ushort4*)&((ushort*)yv)[(size_t)n * 128 + tx * 4] = pk;
        } else {
            *(float4*)&((float*)yv)[(size_t)n * 128 + tx * 4] = make_float4(r0, r1, r2, r3);
        }
    }
}

// ---------------- press (1x3x3 conv over [N,3,D]) + BN stats; a1 is bf16 ----------------

__global__ __launch_bounds__(256) void press_kernel(const ushort* __restrict__ a1,
                                                    const float* __restrict__ a2,
                                                    const float* __restrict__ a3,
                                                    const float* __restrict__ pw,
                                                    const float* __restrict__ pb_,
                                                    float* __restrict__ out,
                                                    float* __restrict__ stats) {
    __shared__ float rows[6 * 128];
    __shared__ float red[512];
    int t = threadIdx.x;
    int d = t & 127, r = t >> 7;
    int n0 = blockIdx.x * 64;
    float w[9];
#pragma unroll
    for (int q = 0; q < 9; q++) w[q] = pw[q];
    float pb = pb_[0];

    float s = 0.f, ss = 0.f;
    for (int it = 0; it < 32; ++it) {
        int npair = n0 + it * 2;
#pragma unroll
        for (int q = 0; q < 3; q++) {
            int idx = q * 256 + t;
            int row = idx >> 7, col = idx & 127;
            int c = row >> 1, rr = row & 1;
            float v;
            size_t off = (size_t)(npair + rr) * 128 + col;
            if (c == 0)      v = bf2f(a1[off]);
            else if (c == 1) v = a2[off];
            else             v = a3[off];
            rows[row * 128 + col] = v;
        }
        __syncthreads();
        const float* R1 = &rows[(0 + r) * 128];
        const float* R2 = &rows[(2 + r) * 128];
        const float* R3 = &rows[(4 + r) * 128];
        float m1 = (d > 0) ? R1[d - 1] : 0.f;
        float m2 = (d > 0) ? R2[d - 1] : 0.f;
        float m3 = (d > 0) ? R3[d - 1] : 0.f;
        float p1 = (d < 127) ? R1[d + 1] : 0.f;
        float p2 = (d < 127) ? R2[d + 1] : 0.f;
        float p3 = (d < 127) ? R3[d + 1] : 0.f;
        float v = pb;
        v = fmaf(w[0], m1, v); v = fmaf(w[1], R1[d], v); v = fmaf(w[2], p1, v);
        v = fmaf(w[3], m2, v); v = fmaf(w[4], R2[d], v); v = fmaf(w[5], p2, v);
        v = fmaf(w[6], m3, v); v = fmaf(w[7], R3[d], v); v = fmaf(w[8], p3, v);
        out[(size_t)(npair + r) * 128 + d] = v;
        s += v; ss += v * v;
        __syncthreads();
    }
    red[t] = s; red[256 + t] = ss;
    __syncthreads();
    if (t < 128) {
        atomicAdd(&stats[6 * 128 + t], red[t] + red[t + 128]);
        atomicAdd(&stats[7 * 128 + t], red[256 + t] + red[256 + t + 128]);
    }
}

// ---------------- graph pooling (gid sorted) ----------------

__global__ __launch_bounds__(256) void pool_kernel(const float* __restrict__ x2,
                                                   const float* __restrict__ x3,
                                                   const float* __restrict__ x4,
                                                   const int* __restrict__ gid,
                                                   float* __restrict__ hg) {
    int t = threadIdx.x;
    int d = t & 127, r = t >> 7;
    int n0 = blockIdx.x * 64;
    float a2 = 0.f, a3 = 0.f, a4 = 0.f;
    int g = gid[n0 + r];
    for (int it = 0; it < 32; ++it) {
        int n = n0 + it * 2 + r;
        int gn = gid[n];
        if (gn != g) {
            atomicAdd(&hg[g * 384 + d], a2);
            atomicAdd(&hg[g * 384 + 128 + d], a3);
            atomicAdd(&hg[g * 384 + 256 + d], a4);
            a2 = a3 = a4 = 0.f;
            g = gn;
        }
        size_t base = (size_t)n * 128 + d;
        a2 += x2[base]; a3 += x3[base]; a4 += x4[base];
    }
    atomicAdd(&hg[g * 384 + d], a2);
    atomicAdd(&hg[g * 384 + 128 + d], a3);
    atomicAdd(&hg[g * 384 + 256 + d], a4);
}

// ---------------- final classifier ----------------

__global__ __launch_bounds__(128) void final_kernel(const float* __restrict__ hg,
                                                    const float* __restrict__ w1,
                                                    const float* __restrict__ b1,
                                                    const float* __restrict__ w2,
                                                    const float* __restrict__ b2,
                                                    float* __restrict__ out) {
    __shared__ float hgs[16 * 384];
    __shared__ float tmp[16 * 128];
    int t = threadIdx.x;
    for (int idx = t; idx < 16 * 384; idx += 128) hgs[idx] = hg[idx];
    __syncthreads();
    for (int g = 0; g < 16; ++g) {
        float acc = b1[t];
        for (int k = 0; k < 384; k++) acc = fmaf(hgs[g * 384 + k], w1[t * 384 + k], acc);
        tmp[g * 128 + t] = acc;
    }
    __syncthreads();
    if (t < 80) {
        int g = t / 5, c = t % 5;
        float acc = b2[c];
        for (int j = 0; j < 128; j++) acc = fmaf(tmp[g * 128 + j], w2[c * 128 + j], acc);
        out[g * 5 + c] = acc;
    }
}

// ---------------- launch ----------------

extern "C" void kernel_launch(void* const* d_in, const int* in_sizes, int n_in,
                              void* d_out, int out_size, void* d_ws, size_t ws_size,
                              hipStream_t stream) {
    (void)in_sizes; (void)n_in; (void)out_size;

    const float* h        = (const float*)d_in[0];
    const float* edge_w   = (const float*)d_in[1];
    const int*   src      = (const int*)d_in[2];
    const int*   dst      = (const int*)d_in[3];
    const int*   node_gid = (const int*)d_in[4];
    const float* c1w = (const float*)d_in[6];
    const float* c1b = (const float*)d_in[7];
    const float* c2w = (const float*)d_in[8];
    const float* c2b = (const float*)d_in[9];
    const float* c3w = (const float*)d_in[10];
    const float* c3b = (const float*)d_in[11];
    const float* pw  = (const float*)d_in[12];
    const float* pb  = (const float*)d_in[13];
    const float* g11w = (const float*)d_in[14];
    const float* g11b = (const float*)d_in[15];
    const float* g12w = (const float*)d_in[16];
    const float* g12b = (const float*)d_in[17];
    const float* g13w = (const float*)d_in[18];
    const float* g13b = (const float*)d_in[19];
    const float* g2w = (const float*)d_in[20];
    const float* g2b = (const float*)d_in[21];
    const float* g3w = (const float*)d_in[22];
    const float* g3b = (const float*)d_in[23];
    const float* g4w = (const float*)d_in[24];
    const float* g4b = (const float*)d_in[25];
    const float* bng = (const float*)d_in[26];
    const float* bnb = (const float*)d_in[27];
    const float* cls1w = (const float*)d_in[28];
    const float* cls1b = (const float*)d_in[29];
    const float* cls2w = (const float*)d_in[30];
    const float* cls2b = (const float*)d_in[31];

    // workspace layout (word offsets chosen so scsh stays 8B-aligned)
    const size_t NW = (size_t)NN * 128;
    float*  A    = (float*)d_ws;            // t1 / a2 / ac_h2
    float*  Bf   = A + NW;                  // t2 / a3 / ac_h3
    float*  Cf   = Bf + NW;                 // t3 / ac_h1 / ac_h4
    ushort* Hb   = (ushort*)(Cf + NW);      // a1 (bf16), NW elems = NW*2 bytes
    int*    csrc = (int*)(Hb + NW);         // E
    float*  cw   = (float*)(csrc + EE);     // E
    float*  stats = (float*)(cw + EE);      // 8*128
    float*  scsh  = stats + 1024;           // 4*256 (8B aligned: even word offset)
    float*  wT    = scsh + 1024;            // 3*3*128*128
    float*  hg    = wT + 147456;            // 16*384
    int*    rp    = (int*)(hg + 16 * 384);  // N+1
    int*    cur   = rp + (NN + 1);          // N
    int*    deg   = cur + NN;               // N
    int*    bsum  = deg + NN;               // 128
    int*    boff  = bsum + 128;             // 128
    size_t required = (size_t)((char*)(boff + 128) - (char*)d_ws);

    if (ws_size < required) {
        // leak ws_size via output: out[0]=bytes, out[1]=MiB
        dbg_kernel<<<1, 128, 0, stream>>>((float*)d_out, (float)ws_size,
                                          (float)(ws_size >> 20));
        return;
    }

    hipMemsetAsync(deg, 0, (size_t)NN * 4, stream);
    hipMemsetAsync(stats, 0, 1024 * 4, stream);
    hipMemsetAsync(hg, 0, (size_t)16 * 384 * 4, stream);

    // CSR build
    hist_kernel<<<EE / 256, 256, 0, stream>>>(dst, deg);
    scanA_kernel<<<128, 1024, 0, stream>>>(deg, rp, bsum);
    scanB_kernel<<<1, 128, 0, stream>>>(bsum, boff);
    scanC_kernel<<<128, 1024, 0, stream>>>(rp, boff);
    hipMemcpyAsync(cur, rp, (size_t)NN * 4, hipMemcpyDeviceToDevice, stream);
    scatter_kernel<<<EE / 256, 256, 0, stream>>>(src, dst, edge_w, cur, csrc, cw);

    // conv path: A=t1, B=t2, C=t3 (+ BN stats for the three combos)
    prepw_kernel<<<576, 256, 0, stream>>>(c1w, c2w, c3w, wT);
    conv_kernel<<<NN / 32, 256, 0, stream>>>(h, wT, c1b, c2b, c3b, A, Bf, Cf, stats);
    bnfin_kernel<<<1, 128, 0, stream>>>(stats, bng, bnb, scsh, 0, 3);

    // fused gconvs; BN folded into gather affine. a1 -> Hb (bf16), a2 -> A, a3 -> B
    gconv_kernel<false, true ><<<NN / 64, 256, 0, stream>>>(A,  rp, csrc, cw, scsh + 0 * 256, g11w, g11b, Hb);
    gconv_kernel<false, false><<<NN / 64, 256, 0, stream>>>(Bf, rp, csrc, cw, scsh + 1 * 256, g12w, g12b, A);
    gconv_kernel<false, false><<<NN / 64, 256, 0, stream>>>(Cf, rp, csrc, cw, scsh + 2 * 256, g13w, g13b, Bf);

    // press(a1,a2,a3) -> C (= ac_h1 pre-BN) + stats
    press_kernel<<<NN / 64, 256, 0, stream>>>(Hb, A, Bf, pw, pb, Cf, stats);
    bnfin_kernel<<<1, 128, 0, stream>>>(stats, bng, bnb, scsh, 3, 1);

    // chained gconvs: ac_h2 -> A, ac_h3 -> B, ac_h4 -> C
    gconv_kernel<false, false><<<NN / 64, 256, 0, stream>>>(Cf, rp, csrc, cw, scsh + 3 * 256, g2w, g2b, A);
    gconv_kernel<false, false><<<NN / 64, 256, 0, stream>>>(A,  rp, csrc, cw, nullptr,       g3w, g3b, Bf);
    gconv_kernel<false, false><<<NN / 64, 256, 0, stream>>>(Bf, rp, csrc, cw, nullptr,       g4w, g4b, Cf);

    // pooling + classifier
    pool_kernel<<<NN / 64, 256, 0, stream>>>(A, Bf, Cf, node_gid, hg);
    final_kernel<<<1, 128, 0, stream>>>(hg, cls1w, cls1b, cls2w, cls2b, (float*)d_out);
}

// Round 3
// 2125.457 us; speedup vs baseline: 1.6607x; 1.6607x over previous
//
#include <hip/hip_runtime.h>
#include <hip/hip_bf16.h>

#define NN 131072
#define EE 2097152
#define EPSS 1e-5f

static __device__ __forceinline__ ushort f2bf(float f) {
    uint u = __float_as_uint(f);
    u += 0x7fffu + ((u >> 16) & 1u);
    return (ushort)(u >> 16);
}
static __device__ __forceinline__ float bf2f(ushort h) {
    return __uint_as_float(((uint)h) << 16);
}

// ---------------- debug: leak ws_size through d_out if workspace too small ----------------

__global__ void dbg_kernel(float* __restrict__ out, float a, float b) {
    int i = threadIdx.x;
    if (i < 80) out[i] = (i == 0) ? a : ((i == 1) ? b : 0.f);
}

// ---------------- CSR build ----------------

__global__ void hist_kernel(const int* __restrict__ dst, int* __restrict__ deg) {
    int e = blockIdx.x * 256 + threadIdx.x;
    if (e < EE) atomicAdd(&deg[dst[e]], 1);
}

__global__ __launch_bounds__(1024) void scanA_kernel(const int* __restrict__ deg,
                                                     int* __restrict__ rp,
                                                     int* __restrict__ bsum) {
    __shared__ int sh[1024];
    int t = threadIdx.x;
    int base = blockIdx.x * 1024;
    int v = deg[base + t];
    sh[t] = v;
    __syncthreads();
    for (int off = 1; off < 1024; off <<= 1) {
        int x = (t >= off) ? sh[t - off] : 0;
        __syncthreads();
        sh[t] += x;
        __syncthreads();
    }
    rp[base + t + 1] = sh[t];
    if (t == 1023) bsum[blockIdx.x] = sh[t];
}

__global__ __launch_bounds__(128) void scanB_kernel(int* __restrict__ bsum, int* __restrict__ boff) {
    __shared__ int sh[128];
    int t = threadIdx.x;
    int v = bsum[t];
    sh[t] = v;
    __syncthreads();
    for (int off = 1; off < 128; off <<= 1) {
        int x = (t >= off) ? sh[t - off] : 0;
        __syncthreads();
        sh[t] += x;
        __syncthreads();
    }
    boff[t] = sh[t] - v;  // exclusive
}

__global__ __launch_bounds__(1024) void scanC_kernel(int* __restrict__ rp, const int* __restrict__ boff) {
    int t = threadIdx.x;
    int b = blockIdx.x;
    rp[b * 1024 + t + 1] += boff[b];
    if (b == 0 && t == 0) rp[0] = 0;
}

__global__ void scatter_kernel(const int* __restrict__ src, const int* __restrict__ dst,
                               const float* __restrict__ ew, int* __restrict__ cur,
                               int2* __restrict__ ecw) {
    int e = blockIdx.x * 256 + threadIdx.x;
    if (e < EE) {
        int n = dst[e];
        int p = atomicAdd(&cur[n], 1);
        ecw[p] = make_int2(src[e], __float_as_int(ew[e]));
    }
}

// ---------------- conv weight transpose: wT[(c*3+k)*16384 + i*128 + o] ----------------

__global__ void prepw_kernel(const float* __restrict__ w1, const float* __restrict__ w2,
                             const float* __restrict__ w3, float* __restrict__ wT) {
    int idx = blockIdx.x * 256 + threadIdx.x;
    if (idx >= 3 * 3 * 128 * 128) return;
    int o = idx & 127;
    int i = (idx >> 7) & 127;
    int ck = idx >> 14;       // c*3+k
    int k = ck % 3;
    int c = ck / 3;
    const float* w = (c == 0) ? w1 : ((c == 1) ? w2 : w3);
    wT[idx] = w[o * 384 + i * 3 + k];
}

// ---------------- fused dilated convs + combine + BN stats (bf16 outputs) ----------------

__global__ __launch_bounds__(256) void conv_kernel(const float* __restrict__ h,
                                                   const float* __restrict__ wT,
                                                   const float* __restrict__ b1,
                                                   const float* __restrict__ b2,
                                                   const float* __restrict__ b3,
                                                   ushort* __restrict__ o1,
                                                   ushort* __restrict__ o2,
                                                   ushort* __restrict__ o3,
                                                   float* __restrict__ stats) {
    __shared__ float xs[38 * 128];
    int t = threadIdx.x;
    int n0 = blockIdx.x * 32;

    for (int idx4 = t; idx4 < 38 * 32; idx4 += 256) {
        int row = idx4 >> 5, c4 = idx4 & 31;
        int gn = n0 - 3 + row;
        float4 v = make_float4(0.f, 0.f, 0.f, 0.f);
        if (gn >= 0 && gn < NN) v = *(const float4*)&h[(size_t)gn * 128 + c4 * 4];
        *(float4*)&xs[row * 128 + c4 * 4] = v;
    }
    __syncthreads();

    int o = t & 127, half = t >> 7;
    int ln0 = half * 16;

    float acc1[16], acc2[16], acc3[16];
#pragma unroll
    for (int j = 0; j < 16; j++) { acc1[j] = 0.f; acc2[j] = 0.f; acc3[j] = 0.f; }

    for (int i = 0; i < 128; i++) {
        const float* wp = wT + (i << 7) + o;
        float w10 = wp[0 * 16384], w11 = wp[1 * 16384], w12 = wp[2 * 16384];
        float w20 = wp[3 * 16384], w21 = wp[4 * 16384], w22 = wp[5 * 16384];
        float w30 = wp[6 * 16384], w31 = wp[7 * 16384], w32 = wp[8 * 16384];

        float buf[8];
#pragma unroll
        for (int p = 0; p < 6; p++) buf[p] = xs[(ln0 + p) * 128 + i];
#pragma unroll
        for (int j = 0; j < 16; j++) {
            buf[(j + 6) & 7] = xs[(ln0 + j + 6) * 128 + i];
            float xm3 = buf[(j + 0) & 7];
            float xm2 = buf[(j + 1) & 7];
            float xm1 = buf[(j + 2) & 7];
            float x0  = buf[(j + 3) & 7];
            float xp1 = buf[(j + 4) & 7];
            float xp2 = buf[(j + 5) & 7];
            float xp3 = buf[(j + 6) & 7];
            acc1[j] = fmaf(w10, xm1, fmaf(w11, x0, fmaf(w12, xp1, acc1[j])));
            acc2[j] = fmaf(w20, xm2, fmaf(w21, x0, fmaf(w22, xp2, acc2[j])));
            acc3[j] = fmaf(w30, xm3, fmaf(w31, x0, fmaf(w32, xp3, acc3[j])));
        }
    }

    float bb1 = b1[o], bb2 = b2[o], bb3 = b3[o];
    float s1 = 0.f, ss1 = 0.f, s2 = 0.f, ss2 = 0.f, s3 = 0.f, ss3 = 0.f;
#pragma unroll
    for (int j = 0; j < 16; j++) {
        int n = n0 + ln0 + j;
        float c1 = acc1[j] + bb1;
        float c2 = acc2[j] + bb2;
        float c3 = acc3[j] + bb3;
        float t1 = fmaxf(c1, 0.f) + c2;
        float t2 = fmaxf(c2, 0.f) + c3;
        float t3 = fmaxf(c3, 0.f) + c1;
        size_t base = (size_t)n * 128 + o;
        o1[base] = f2bf(t1); o2[base] = f2bf(t2); o3[base] = f2bf(t3);
        s1 += t1; ss1 += t1 * t1;
        s2 += t2; ss2 += t2 * t2;
        s3 += t3; ss3 += t3 * t3;
    }

    __syncthreads();
    float* red = xs;
    red[0 * 256 + t] = s1; red[1 * 256 + t] = ss1;
    red[2 * 256 + t] = s2; red[3 * 256 + t] = ss2;
    red[4 * 256 + t] = s3; red[5 * 256 + t] = ss3;
    __syncthreads();
    if (t < 128) {
#pragma unroll
        for (int p = 0; p < 6; p++)
            atomicAdd(&stats[p * 128 + t], red[p * 256 + t] + red[p * 256 + t + 128]);
    }
}

// ---------------- BN finalize ----------------

__global__ __launch_bounds__(128) void bnfin_kernel(const float* __restrict__ stats,
                                                    const float* __restrict__ g,
                                                    const float* __restrict__ b,
                                                    float* __restrict__ scsh, int q0, int nq) {
    int d = threadIdx.x;
    for (int q = q0; q < q0 + nq; ++q) {
        float s  = stats[(2 * q) * 128 + d];
        float ss = stats[(2 * q + 1) * 128 + d];
        float mu  = s * (1.f / NN);
        float var = ss * (1.f / NN) - mu * mu;
        float sc = g[d] / sqrtf(var + EPSS);
        float sh = b[d] - mu * sc;
        scsh[q * 256 + d] = sc;
        scsh[q * 256 + 128 + d] = sh;
    }
}

// ---------------- fused gconv: CSR gather (+BN affine) + GEMM + bias + relu ----------------
// block = 32 dst nodes, 256 threads. Phase 1: wave w aggregates nodes [w*8, w*8+8)
// (lane = 2 bf16 features) into LDS aggs[32][128] fp32. Phase 2: GEMM y = relu(aggs @ W + b) -> bf16.

__global__ __launch_bounds__(256) void gconv_kernel(const ushort* __restrict__ xb,
                                                    const int* __restrict__ rp,
                                                    const int2* __restrict__ ecw,
                                                    const float* __restrict__ scsh,
                                                    const float* __restrict__ W,
                                                    const float* __restrict__ bias,
                                                    ushort* __restrict__ yb) {
    __shared__ float aggs[32 * 128];
    __shared__ float WC[32 * 128];
    int t = threadIdx.x;
    int n0 = blockIdx.x * 32;
    int wv = t >> 6, lane = t & 63;
    const uint laneoff = lane * 2;

    float scx = 1.f, scy = 1.f, shx = 0.f, shy = 0.f;
    if (scsh) {
        float2 sc = *(const float2*)&scsh[laneoff];
        float2 sh = *(const float2*)&scsh[128 + laneoff];
        scx = sc.x; scy = sc.y; shx = sh.x; shy = sh.y;
    }

    for (int k = 0; k < 8; k++) {
        int n = n0 + wv * 8 + k;
        int beg = rp[n], end = rp[n + 1];
        float ax = 0.f, ay = 0.f, sw = 0.f;
        int e = beg;
        for (; e + 8 <= end; e += 8) {
            uint u[8]; float ww[8];
#pragma unroll
            for (int q = 0; q < 8; q++) {
                int2 ec = ecw[e + q];
                ww[q] = __int_as_float(ec.y);
                u[q] = *(const uint*)&xb[((uint)ec.x << 7) + laneoff];
            }
#pragma unroll
            for (int q = 0; q < 8; q++) {
                ax = fmaf(ww[q], __uint_as_float(u[q] << 16), ax);
                ay = fmaf(ww[q], __uint_as_float(u[q] & 0xffff0000u), ay);
                sw += ww[q];
            }
        }
        for (; e < end; e++) {
            int2 ec = ecw[e];
            float w0 = __int_as_float(ec.y);
            uint u0 = *(const uint*)&xb[((uint)ec.x << 7) + laneoff];
            ax = fmaf(w0, __uint_as_float(u0 << 16), ax);
            ay = fmaf(w0, __uint_as_float(u0 & 0xffff0000u), ay);
            sw += w0;
        }
        if (scsh) {
            ax = fmaf(sw, shx, ax * scx);
            ay = fmaf(sw, shy, ay * scy);
        }
        *(float2*)&aggs[(wv * 8 + k) * 128 + laneoff] = make_float2(ax, ay);
    }
    __syncthreads();

    int tx = t & 31, ty = t >> 5;   // ty in [0,8): 4 nodes each; tx: 4 feats
    float acc[4][4];
#pragma unroll
    for (int j = 0; j < 4; j++)
#pragma unroll
        for (int q = 0; q < 4; q++) acc[j][q] = 0.f;

    for (int ic = 0; ic < 128; ic += 32) {
#pragma unroll
        for (int rep = 0; rep < 4; rep++) {
            int idx = rep * 256 + t;
            int i = idx >> 5, o4 = idx & 31;
            *(float4*)&WC[i * 128 + o4 * 4] = *(const float4*)&W[(size_t)(ic + i) * 128 + o4 * 4];
        }
        __syncthreads();
#pragma unroll
        for (int i4 = 0; i4 < 8; i4++) {
            float4 w0 = *(float4*)&WC[(i4 * 4 + 0) * 128 + tx * 4];
            float4 w1 = *(float4*)&WC[(i4 * 4 + 1) * 128 + tx * 4];
            float4 w2 = *(float4*)&WC[(i4 * 4 + 2) * 128 + tx * 4];
            float4 w3 = *(float4*)&WC[(i4 * 4 + 3) * 128 + tx * 4];
#pragma unroll
            for (int j = 0; j < 4; j++) {
                float4 a = *(float4*)&aggs[(ty * 4 + j) * 128 + ic + i4 * 4];
                acc[j][0] = fmaf(a.x, w0.x, fmaf(a.y, w1.x, fmaf(a.z, w2.x, fmaf(a.w, w3.x, acc[j][0]))));
                acc[j][1] = fmaf(a.x, w0.y, fmaf(a.y, w1.y, fmaf(a.z, w2.y, fmaf(a.w, w3.y, acc[j][1]))));
                acc[j][2] = fmaf(a.x, w0.z, fmaf(a.y, w1.z, fmaf(a.z, w2.z, fmaf(a.w, w3.z, acc[j][2]))));
                acc[j][3] = fmaf(a.x, w0.w, fmaf(a.y, w1.w, fmaf(a.z, w2.w, fmaf(a.w, w3.w, acc[j][3]))));
            }
        }
        __syncthreads();
    }

    float4 bv = *(const float4*)&bias[tx * 4];
#pragma unroll
    for (int j = 0; j < 4; j++) {
        float r0 = fmaxf(acc[j][0] + bv.x, 0.f);
        float r1 = fmaxf(acc[j][1] + bv.y, 0.f);
        float r2 = fmaxf(acc[j][2] + bv.z, 0.f);
        float r3 = fmaxf(acc[j][3] + bv.w, 0.f);
        ushort4 pk;
        pk.x = f2bf(r0); pk.y = f2bf(r1); pk.z = f2bf(r2); pk.w = f2bf(r3);
        *(ushort4*)&yb[(size_t)(n0 + ty * 4 + j) * 128 + tx * 4] = pk;
    }
}

// ---------------- press (1x3x3 conv over [N,3,D]) + BN stats (all bf16 I/O) ----------------

__global__ __launch_bounds__(256) void press_kernel(const ushort* __restrict__ a1,
                                                    const ushort* __restrict__ a2,
                                                    const ushort* __restrict__ a3,
                                                    const float* __restrict__ pw,
                                                    const float* __restrict__ pb_,
                                                    ushort* __restrict__ out,
                                                    float* __restrict__ stats) {
    __shared__ float rows[6 * 128];
    __shared__ float red[512];
    int t = threadIdx.x;
    int d = t & 127, r = t >> 7;
    int n0 = blockIdx.x * 64;
    float w[9];
#pragma unroll
    for (int q = 0; q < 9; q++) w[q] = pw[q];
    float pb = pb_[0];

    float s = 0.f, ss = 0.f;
    for (int it = 0; it < 32; ++it) {
        int npair = n0 + it * 2;
#pragma unroll
        for (int q = 0; q < 3; q++) {
            int idx = q * 256 + t;
            int row = idx >> 7, col = idx & 127;
            int c = row >> 1, rr = row & 1;
            size_t off = (size_t)(npair + rr) * 128 + col;
            ushort v = (c == 0) ? a1[off] : ((c == 1) ? a2[off] : a3[off]);
            rows[row * 128 + col] = bf2f(v);
        }
        __syncthreads();
        const float* R1 = &rows[(0 + r) * 128];
        const float* R2 = &rows[(2 + r) * 128];
        const float* R3 = &rows[(4 + r) * 128];
        float m1 = (d > 0) ? R1[d - 1] : 0.f;
        float m2 = (d > 0) ? R2[d - 1] : 0.f;
        float m3 = (d > 0) ? R3[d - 1] : 0.f;
        float p1 = (d < 127) ? R1[d + 1] : 0.f;
        float p2 = (d < 127) ? R2[d + 1] : 0.f;
        float p3 = (d < 127) ? R3[d + 1] : 0.f;
        float v = pb;
        v = fmaf(w[0], m1, v); v = fmaf(w[1], R1[d], v); v = fmaf(w[2], p1, v);
        v = fmaf(w[3], m2, v); v = fmaf(w[4], R2[d], v); v = fmaf(w[5], p2, v);
        v = fmaf(w[6], m3, v); v = fmaf(w[7], R3[d], v); v = fmaf(w[8], p3, v);
        out[(size_t)(npair + r) * 128 + d] = f2bf(v);
        s += v; ss += v * v;
        __syncthreads();
    }
    red[t] = s; red[256 + t] = ss;
    __syncthreads();
    if (t < 128) {
        atomicAdd(&stats[6 * 128 + t], red[t] + red[t + 128]);
        atomicAdd(&stats[7 * 128 + t], red[256 + t] + red[256 + t + 128]);
    }
}

// ---------------- graph pooling (gid sorted), bf16 inputs ----------------

__global__ __launch_bounds__(256) void pool_kernel(const ushort* __restrict__ x2,
                                                   const ushort* __restrict__ x3,
                                                   const ushort* __restrict__ x4,
                                                   const int* __restrict__ gid,
                                                   float* __restrict__ hg) {
    int t = threadIdx.x;
    int d = t & 127, r = t >> 7;
    int n0 = blockIdx.x * 64;
    float a2 = 0.f, a3 = 0.f, a4 = 0.f;
    int g = gid[n0 + r];
    for (int it = 0; it < 32; ++it) {
        int n = n0 + it * 2 + r;
        int gn = gid[n];
        if (gn != g) {
            atomicAdd(&hg[g * 384 + d], a2);
            atomicAdd(&hg[g * 384 + 128 + d], a3);
            atomicAdd(&hg[g * 384 + 256 + d], a4);
            a2 = a3 = a4 = 0.f;
            g = gn;
        }
        size_t base = (size_t)n * 128 + d;
        a2 += bf2f(x2[base]); a3 += bf2f(x3[base]); a4 += bf2f(x4[base]);
    }
    atomicAdd(&hg[g * 384 + d], a2);
    atomicAdd(&hg[g * 384 + 128 + d], a3);
    atomicAdd(&hg[g * 384 + 256 + d], a4);
}

// ---------------- final classifier ----------------

__global__ __launch_bounds__(128) void final_kernel(const float* __restrict__ hg,
                                                    const float* __restrict__ w1,
                                                    const float* __restrict__ b1,
                                                    const float* __restrict__ w2,
                                                    const float* __restrict__ b2,
                                                    float* __restrict__ out) {
    __shared__ float hgs[16 * 384];
    __shared__ float tmp[16 * 128];
    int t = threadIdx.x;
    for (int idx = t; idx < 16 * 384; idx += 128) hgs[idx] = hg[idx];
    __syncthreads();
    for (int g = 0; g < 16; ++g) {
        float acc = b1[t];
        for (int k = 0; k < 384; k++) acc = fmaf(hgs[g * 384 + k], w1[t * 384 + k], acc);
        tmp[g * 128 + t] = acc;
    }
    __syncthreads();
    if (t < 80) {
        int g = t / 5, c = t % 5;
        float acc = b2[c];
        for (int j = 0; j < 128; j++) acc = fmaf(tmp[g * 128 + j], w2[c * 128 + j], acc);
        out[g * 5 + c] = acc;
    }
}

// ---------------- launch ----------------

extern "C" void kernel_launch(void* const* d_in, const int* in_sizes, int n_in,
                              void* d_out, int out_size, void* d_ws, size_t ws_size,
                              hipStream_t stream) {
    (void)in_sizes; (void)n_in; (void)out_size;

    const float* h        = (const float*)d_in[0];
    const float* edge_w   = (const float*)d_in[1];
    const int*   src      = (const int*)d_in[2];
    const int*   dst      = (const int*)d_in[3];
    const int*   node_gid = (const int*)d_in[4];
    const float* c1w = (const float*)d_in[6];
    const float* c1b = (const float*)d_in[7];
    const float* c2w = (const float*)d_in[8];
    const float* c2b = (const float*)d_in[9];
    const float* c3w = (const float*)d_in[10];
    const float* c3b = (const float*)d_in[11];
    const float* pw  = (const float*)d_in[12];
    const float* pb  = (const float*)d_in[13];
    const float* g11w = (const float*)d_in[14];
    const float* g11b = (const float*)d_in[15];
    const float* g12w = (const float*)d_in[16];
    const float* g12b = (const float*)d_in[17];
    const float* g13w = (const float*)d_in[18];
    const float* g13b = (const float*)d_in[19];
    const float* g2w = (const float*)d_in[20];
    const float* g2b = (const float*)d_in[21];
    const float* g3w = (const float*)d_in[22];
    const float* g3b = (const float*)d_in[23];
    const float* g4w = (const float*)d_in[24];
    const float* g4b = (const float*)d_in[25];
    const float* bng = (const float*)d_in[26];
    const float* bnb = (const float*)d_in[27];
    const float* cls1w = (const float*)d_in[28];
    const float* cls1b = (const float*)d_in[29];
    const float* cls2w = (const float*)d_in[30];
    const float* cls2b = (const float*)d_in[31];

    // workspace layout: 4 bf16 [N,128] buffers with rotation + CSR + misc
    const size_t NW = (size_t)NN * 128;
    ushort* U1 = (ushort*)d_ws;
    ushort* U2 = U1 + NW;
    ushort* U3 = U2 + NW;
    ushort* U4 = U3 + NW;
    int2*   ecw = (int2*)(U4 + NW);          // E * 8B
    float*  stats = (float*)(ecw + EE);      // 8*128
    float*  scsh  = stats + 1024;            // 4*256
    float*  wT    = scsh + 1024;             // 3*3*128*128
    float*  hg    = wT + 147456;             // 16*384
    int*    rp    = (int*)(hg + 16 * 384);   // N+1
    int*    cur   = rp + (NN + 1);           // N
    int*    deg   = cur + NN;                // N
    int*    bsum  = deg + NN;                // 128
    int*    boff  = bsum + 128;              // 128
    size_t required = (size_t)((char*)(boff + 128) - (char*)d_ws);

    if (ws_size < required) {
        dbg_kernel<<<1, 128, 0, stream>>>((float*)d_out, (float)ws_size,
                                          (float)(ws_size >> 20));
        return;
    }

    hipMemsetAsync(deg, 0, (size_t)NN * 4, stream);
    hipMemsetAsync(stats, 0, 1024 * 4, stream);
    hipMemsetAsync(hg, 0, (size_t)16 * 384 * 4, stream);

    // CSR build
    hist_kernel<<<EE / 256, 256, 0, stream>>>(dst, deg);
    scanA_kernel<<<128, 1024, 0, stream>>>(deg, rp, bsum);
    scanB_kernel<<<1, 128, 0, stream>>>(bsum, boff);
    scanC_kernel<<<128, 1024, 0, stream>>>(rp, boff);
    hipMemcpyAsync(cur, rp, (size_t)NN * 4, hipMemcpyDeviceToDevice, stream);
    scatter_kernel<<<EE / 256, 256, 0, stream>>>(src, dst, edge_w, cur, ecw);

    // conv path: U1=t1, U2=t2, U3=t3 (bf16) + BN stats
    prepw_kernel<<<576, 256, 0, stream>>>(c1w, c2w, c3w, wT);
    conv_kernel<<<NN / 32, 256, 0, stream>>>(h, wT, c1b, c2b, c3b, U1, U2, U3, stats);
    bnfin_kernel<<<1, 128, 0, stream>>>(stats, bng, bnb, scsh, 0, 3);

    // first three gconvs (BN folded into gather affine)
    gconv_kernel<<<NN / 32, 256, 0, stream>>>(U1, rp, ecw, scsh + 0 * 256, g11w, g11b, U4); // a1
    gconv_kernel<<<NN / 32, 256, 0, stream>>>(U2, rp, ecw, scsh + 1 * 256, g12w, g12b, U1); // a2
    gconv_kernel<<<NN / 32, 256, 0, stream>>>(U3, rp, ecw, scsh + 2 * 256, g13w, g13b, U2); // a3

    // press(a1,a2,a3) -> U3 (= ac_h1 pre-BN) + stats
    press_kernel<<<NN / 64, 256, 0, stream>>>(U4, U1, U2, pw, pb, U3, stats);
    bnfin_kernel<<<1, 128, 0, stream>>>(stats, bng, bnb, scsh, 3, 1);

    // chained gconvs: ac_h2 -> U4, ac_h3 -> U1, ac_h4 -> U2
    gconv_kernel<<<NN / 32, 256, 0, stream>>>(U3, rp, ecw, scsh + 3 * 256, g2w, g2b, U4);
    gconv_kernel<<<NN / 32, 256, 0, stream>>>(U4, rp, ecw, nullptr,        g3w, g3b, U1);
    gconv_kernel<<<NN / 32, 256, 0, stream>>>(U1, rp, ecw, nullptr,        g4w, g4b, U2);

    // pooling + classifier
    pool_kernel<<<NN / 64, 256, 0, stream>>>(U4, U1, U2, node_gid, hg);
    final_kernel<<<1, 128, 0, stream>>>(hg, cls1w, cls1b, cls2w, cls2b, (float*)d_out);
}

// Round 4
// 1604.007 us; speedup vs baseline: 2.2005x; 1.3251x over previous
//
#include <hip/hip_runtime.h>
#include <hip/hip_bf16.h>

#define NN 131072
#define EE 2097152
#define EPSS 1e-5f

typedef float f32x4 __attribute__((ext_vector_type(4)));
typedef short s16x8 __attribute__((ext_vector_type(8)));

static __device__ __forceinline__ ushort f2bf(float f) {
    uint u = __float_as_uint(f);
    u += 0x7fffu + ((u >> 16) & 1u);
    return (ushort)(u >> 16);
}
static __device__ __forceinline__ float bf2f(ushort h) {
    return __uint_as_float(((uint)h) << 16);
}

// ---------------- debug: leak ws_size through d_out if workspace too small ----------------

__global__ void dbg_kernel(float* __restrict__ out, float a, float b) {
    int i = threadIdx.x;
    if (i < 80) out[i] = (i == 0) ? a : ((i == 1) ? b : 0.f);
}

// ---------------- CSR build ----------------

__global__ void hist_kernel(const int* __restrict__ dst, int* __restrict__ deg) {
    int e = blockIdx.x * 256 + threadIdx.x;
    if (e < EE) atomicAdd(&deg[dst[e]], 1);
}

__global__ __launch_bounds__(1024) void scanA_kernel(const int* __restrict__ deg,
                                                     int* __restrict__ rp,
                                                     int* __restrict__ bsum) {
    __shared__ int sh[1024];
    int t = threadIdx.x;
    int base = blockIdx.x * 1024;
    int v = deg[base + t];
    sh[t] = v;
    __syncthreads();
    for (int off = 1; off < 1024; off <<= 1) {
        int x = (t >= off) ? sh[t - off] : 0;
        __syncthreads();
        sh[t] += x;
        __syncthreads();
    }
    rp[base + t + 1] = sh[t];
    if (t == 1023) bsum[blockIdx.x] = sh[t];
}

__global__ __launch_bounds__(128) void scanB_kernel(int* __restrict__ bsum, int* __restrict__ boff) {
    __shared__ int sh[128];
    int t = threadIdx.x;
    int v = bsum[t];
    sh[t] = v;
    __syncthreads();
    for (int off = 1; off < 128; off <<= 1) {
        int x = (t >= off) ? sh[t - off] : 0;
        __syncthreads();
        sh[t] += x;
        __syncthreads();
    }
    boff[t] = sh[t] - v;  // exclusive
}

__global__ __launch_bounds__(1024) void scanC_kernel(int* __restrict__ rp, const int* __restrict__ boff) {
    int t = threadIdx.x;
    int b = blockIdx.x;
    rp[b * 1024 + t + 1] += boff[b];
    if (b == 0 && t == 0) rp[0] = 0;
}

__global__ void scatter_kernel(const int* __restrict__ src, const int* __restrict__ dst,
                               const float* __restrict__ ew, int* __restrict__ cur,
                               int2* __restrict__ ecw) {
    int e = blockIdx.x * 256 + threadIdx.x;
    if (e < EE) {
        int n = dst[e];
        int p = atomicAdd(&cur[n], 1);
        ecw[p] = make_int2(src[e], __float_as_int(ew[e]));
    }
}

// ---------------- weight prep: bf16 MFMA B-fragment layouts ----------------
// layout: [ck][kc(4)][ot(8)][lane(64)][j(8)], elem = W[i= kc*32+(lane>>4)*8+j][o= ot*16+(lane&15)]

__global__ void prepw_conv(const float* __restrict__ w1, const float* __restrict__ w2,
                           const float* __restrict__ w3, ushort* __restrict__ wTb) {
    int idx = blockIdx.x * 256 + threadIdx.x;
    if (idx >= 9 * 16384) return;
    int j = idx & 7;
    int lane = (idx >> 3) & 63;
    int ot = (idx >> 9) & 7;
    int kc = (idx >> 12) & 3;
    int ck = idx >> 14;            // c*3+k
    int k = ck % 3, c = ck / 3;
    int i = kc * 32 + (lane >> 4) * 8 + j;
    int o = ot * 16 + (lane & 15);
    const float* w = (c == 0) ? w1 : ((c == 1) ? w2 : w3);
    wTb[idx] = f2bf(w[o * 384 + i * 3 + k]);
}

__global__ void prepw_g(const float* __restrict__ w0, const float* __restrict__ w1,
                        const float* __restrict__ w2, const float* __restrict__ w3,
                        const float* __restrict__ w4, const float* __restrict__ w5,
                        ushort* __restrict__ wGb) {
    int idx = blockIdx.x * 256 + threadIdx.x;
    if (idx >= 6 * 16384) return;
    int j = idx & 7;
    int lane = (idx >> 3) & 63;
    int ot = (idx >> 9) & 7;
    int kc = (idx >> 12) & 3;
    int m = idx >> 14;
    int i = kc * 32 + (lane >> 4) * 8 + j;
    int o = ot * 16 + (lane & 15);
    const float* w = (m == 0) ? w0 : ((m == 1) ? w1 : ((m == 2) ? w2 :
                     ((m == 3) ? w3 : ((m == 4) ? w4 : w5))));
    wGb[idx] = f2bf(w[i * 128 + o]);
}

// ---------------- fused dilated convs via MFMA + combine + BN stats ----------------
// block = 64 nodes, 4 waves; wave w: nodes [w*16, w*16+16), full 128 outputs.
// LDS: 70 rows (halo 3 each side) x 128ch bf16, XOR-swizzled (byte ^= (row&7)<<4).

__global__ __launch_bounds__(256) void conv_kernel(const float* __restrict__ h,
        const ushort* __restrict__ wTb,
        const float* __restrict__ b1, const float* __restrict__ b2, const float* __restrict__ b3,
        ushort* __restrict__ o1, ushort* __restrict__ o2, ushort* __restrict__ o3,
        float* __restrict__ stats) {
    __shared__ char smem[17920];
    __shared__ float red[768];
    int t = threadIdx.x;
    int n0 = blockIdx.x * 64;

    for (int idx = t; idx < 768; idx += 256) red[idx] = 0.f;

    for (int idx = t; idx < 70 * 32; idx += 256) {
        int row = idx >> 5, c4 = idx & 31;
        int gn = n0 - 3 + row;
        float4 v = make_float4(0.f, 0.f, 0.f, 0.f);
        if (gn >= 0 && gn < NN) v = *(const float4*)&h[(size_t)gn * 128 + c4 * 4];
        ushort4 pk;
        pk.x = f2bf(v.x); pk.y = f2bf(v.y); pk.z = f2bf(v.z); pk.w = f2bf(v.w);
        int off = (row * 256 + c4 * 8) ^ ((row & 7) << 4);
        *(ushort4*)(smem + off) = pk;
    }
    __syncthreads();

    int wv = t >> 6, lane = t & 63;
    int fbase = lane & 15, grp = lane >> 4;
    int rbase = wv * 16 + fbase + 3;
    int cbb = grp << 4;

    f32x4 acc[3][8];
#pragma unroll
    for (int c = 0; c < 3; c++)
#pragma unroll
        for (int ot = 0; ot < 8; ot++) acc[c][ot] = (f32x4){0.f, 0.f, 0.f, 0.f};

#pragma unroll
    for (int ck = 0; ck < 9; ck++) {
        const int c = ck / 3, k = ck % 3;
        const int shift = (c + 1) * (k - 1);
        int rr = rbase + shift;
        int sw = (rr & 7) << 4;
#pragma unroll
        for (int kc = 0; kc < 4; kc++) {
            s16x8 a = *(const s16x8*)(smem + ((rr * 256 + kc * 64 + cbb) ^ sw));
#pragma unroll
            for (int ot = 0; ot < 8; ot++) {
                s16x8 b = *(const s16x8*)(wTb + ((ck * 4 + kc) * 8 + ot) * 512 + lane * 8);
                acc[c][ot] = __builtin_amdgcn_mfma_f32_16x16x32_bf16(a, b, acc[c][ot], 0, 0, 0);
            }
        }
    }

    __syncthreads();   // done reading staged x; reuse smem for output transpose

    int nlb = wv * 16 + grp * 4;
#pragma unroll
    for (int p = 0; p < 3; p++) {
        const int pa = p, pb = (p + 1) % 3;
        const float* Ba = (p == 0) ? b1 : ((p == 1) ? b2 : b3);
        const float* Bb = (p == 0) ? b2 : ((p == 1) ? b3 : b1);
        ushort* Op = (p == 0) ? o1 : ((p == 1) ? o2 : o3);
#pragma unroll
        for (int ot = 0; ot < 8; ot++) {
            int f = ot * 16 + fbase;
            float bba = Ba[f], bbb = Bb[f];
            float s = 0.f, ss = 0.f;
#pragma unroll
            for (int q = 0; q < 4; q++) {
                float ca = acc[pa][ot][q] + bba;
                float cb = acc[pb][ot][q] + bbb;
                float tv = fmaxf(ca, 0.f) + cb;
                int nl = nlb + q;
                int off = (nl * 256 + f * 2) ^ ((nl & 7) << 4);
                *(ushort*)(smem + off) = f2bf(tv);
                s += tv; ss += tv * tv;
            }
            s  += __shfl_xor(s, 16);  s  += __shfl_xor(s, 32);
            ss += __shfl_xor(ss, 16); ss += __shfl_xor(ss, 32);
            if (lane < 16) {
                atomicAdd(&red[(2 * p) * 128 + f], s);
                atomicAdd(&red[(2 * p + 1) * 128 + f], ss);
            }
        }
        __syncthreads();
        for (int idx = t; idx < 1024; idx += 256) {
            int row = idx >> 4, c16 = idx & 15;
            uint4 v = *(const uint4*)(smem + ((row * 256 + c16 * 16) ^ ((row & 7) << 4)));
            *(uint4*)&Op[(size_t)(n0 + row) * 128 + c16 * 8] = v;
        }
        __syncthreads();
    }

    if (t < 128) {
#pragma unroll
        for (int p6 = 0; p6 < 6; p6++)
            atomicAdd(&stats[p6 * 128 + t], red[p6 * 128 + t]);
    }
}

// ---------------- BN finalize ----------------

__global__ __launch_bounds__(128) void bnfin_kernel(const float* __restrict__ stats,
                                                    const float* __restrict__ g,
                                                    const float* __restrict__ b,
                                                    float* __restrict__ scsh, int q0, int nq) {
    int d = threadIdx.x;
    for (int q = q0; q < q0 + nq; ++q) {
        float s  = stats[(2 * q) * 128 + d];
        float ss = stats[(2 * q + 1) * 128 + d];
        float mu  = s * (1.f / NN);
        float var = ss * (1.f / NN) - mu * mu;
        float sc = g[d] / sqrtf(var + EPSS);
        float sh = b[d] - mu * sc;
        scsh[q * 256 + d] = sc;
        scsh[q * 256 + 128 + d] = sh;
    }
}

// ---------------- standalone CSR gather (+BN affine), one wave per node, no LDS ----------------

__global__ __launch_bounds__(256) void gather_kernel(const ushort* __restrict__ xb,
        const int* __restrict__ rp, const int2* __restrict__ ecw,
        const float* __restrict__ scsh, ushort* __restrict__ G) {
    int t = threadIdx.x;
    int wid = blockIdx.x * 4 + (t >> 6);
    int lane = t & 63;
    uint laneoff = lane * 2;
    float scx = 1.f, scy = 1.f, shx = 0.f, shy = 0.f;
    if (scsh) {
        float2 sc = *(const float2*)&scsh[laneoff];
        float2 sh = *(const float2*)&scsh[128 + laneoff];
        scx = sc.x; scy = sc.y; shx = sh.x; shy = sh.y;
    }
    int beg = rp[wid], end = rp[wid + 1];
    float ax = 0.f, ay = 0.f, sw = 0.f;
    int e = beg;
    for (; e + 8 <= end; e += 8) {
        uint u[8]; float ww[8];
#pragma unroll
        for (int q = 0; q < 8; q++) {
            int2 ec = ecw[e + q];
            ww[q] = __int_as_float(ec.y);
            u[q] = *(const uint*)&xb[((uint)ec.x << 7) + laneoff];
        }
#pragma unroll
        for (int q = 0; q < 8; q++) {
            ax = fmaf(ww[q], __uint_as_float(u[q] << 16), ax);
            ay = fmaf(ww[q], __uint_as_float(u[q] & 0xffff0000u), ay);
            sw += ww[q];
        }
    }
    for (; e < end; e++) {
        int2 ec = ecw[e];
        float w0 = __int_as_float(ec.y);
        uint u0 = *(const uint*)&xb[((uint)ec.x << 7) + laneoff];
        ax = fmaf(w0, __uint_as_float(u0 << 16), ax);
        ay = fmaf(w0, __uint_as_float(u0 & 0xffff0000u), ay);
        sw += w0;
    }
    if (scsh) {
        ax = fmaf(sw, shx, ax * scx);
        ay = fmaf(sw, shy, ay * scy);
    }
    uint pk = (uint)f2bf(ax) | ((uint)f2bf(ay) << 16);
    *(uint*)&G[(size_t)wid * 128 + laneoff] = pk;
}

// ---------------- MFMA GEMM: Y = relu(X @ W + b), bf16 in/out ----------------

__global__ __launch_bounds__(256) void gemm_kernel(const ushort* __restrict__ X,
        const ushort* __restrict__ wF, const float* __restrict__ bias,
        ushort* __restrict__ Y) {
    __shared__ char smem[16384];
    int t = threadIdx.x;
    int n0 = blockIdx.x * 64;
    for (int idx = t; idx < 1024; idx += 256) {
        int row = idx >> 4, c16 = idx & 15;
        uint4 v = *(const uint4*)&X[(size_t)(n0 + row) * 128 + c16 * 8];
        *(uint4*)(smem + ((row * 256 + c16 * 16) ^ ((row & 7) << 4))) = v;
    }
    __syncthreads();

    int wv = t >> 6, lane = t & 63;
    int fbase = lane & 15, grp = lane >> 4;
    int rr = wv * 16 + fbase;
    int sw = (rr & 7) << 4;
    int cbb = grp << 4;

    f32x4 acc[8];
#pragma unroll
    for (int ot = 0; ot < 8; ot++) acc[ot] = (f32x4){0.f, 0.f, 0.f, 0.f};

#pragma unroll
    for (int kc = 0; kc < 4; kc++) {
        s16x8 a = *(const s16x8*)(smem + ((rr * 256 + kc * 64 + cbb) ^ sw));
#pragma unroll
        for (int ot = 0; ot < 8; ot++) {
            s16x8 b = *(const s16x8*)(wF + (kc * 8 + ot) * 512 + lane * 8);
            acc[ot] = __builtin_amdgcn_mfma_f32_16x16x32_bf16(a, b, acc[ot], 0, 0, 0);
        }
    }

    __syncthreads();
    int nlb = wv * 16 + grp * 4;
#pragma unroll
    for (int ot = 0; ot < 8; ot++) {
        int f = ot * 16 + fbase;
        float bb = bias[f];
#pragma unroll
        for (int q = 0; q < 4; q++) {
            float y = fmaxf(acc[ot][q] + bb, 0.f);
            int nl = nlb + q;
            *(ushort*)(smem + ((nl * 256 + f * 2) ^ ((nl & 7) << 4))) = f2bf(y);
        }
    }
    __syncthreads();
    for (int idx = t; idx < 1024; idx += 256) {
        int row = idx >> 4, c16 = idx & 15;
        uint4 v = *(const uint4*)(smem + ((row * 256 + c16 * 16) ^ ((row & 7) << 4)));
        *(uint4*)&Y[(size_t)(n0 + row) * 128 + c16 * 8] = v;
    }
}

// ---------------- press (1x3x3 conv over [N,3,D]) + BN stats (bf16 I/O) ----------------

__global__ __launch_bounds__(256) void press_kernel(const ushort* __restrict__ a1,
                                                    const ushort* __restrict__ a2,
                                                    const ushort* __restrict__ a3,
                                                    const float* __restrict__ pw,
                                                    const float* __restrict__ pb_,
                                                    ushort* __restrict__ out,
                                                    float* __restrict__ stats) {
    __shared__ float rows[6 * 128];
    __shared__ float red[512];
    int t = threadIdx.x;
    int d = t & 127, r = t >> 7;
    int n0 = blockIdx.x * 64;
    float w[9];
#pragma unroll
    for (int q = 0; q < 9; q++) w[q] = pw[q];
    float pb = pb_[0];

    float s = 0.f, ss = 0.f;
    for (int it = 0; it < 32; ++it) {
        int npair = n0 + it * 2;
#pragma unroll
        for (int q = 0; q < 3; q++) {
            int idx = q * 256 + t;
            int row = idx >> 7, col = idx & 127;
            int c = row >> 1, rr = row & 1;
            size_t off = (size_t)(npair + rr) * 128 + col;
            ushort v = (c == 0) ? a1[off] : ((c == 1) ? a2[off] : a3[off]);
            rows[row * 128 + col] = bf2f(v);
        }
        __syncthreads();
        const float* R1 = &rows[(0 + r) * 128];
        const float* R2 = &rows[(2 + r) * 128];
        const float* R3 = &rows[(4 + r) * 128];
        float m1 = (d > 0) ? R1[d - 1] : 0.f;
        float m2 = (d > 0) ? R2[d - 1] : 0.f;
        float m3 = (d > 0) ? R3[d - 1] : 0.f;
        float p1 = (d < 127) ? R1[d + 1] : 0.f;
        float p2 = (d < 127) ? R2[d + 1] : 0.f;
        float p3 = (d < 127) ? R3[d + 1] : 0.f;
        float v = pb;
        v = fmaf(w[0], m1, v); v = fmaf(w[1], R1[d], v); v = fmaf(w[2], p1, v);
        v = fmaf(w[3], m2, v); v = fmaf(w[4], R2[d], v); v = fmaf(w[5], p2, v);
        v = fmaf(w[6], m3, v); v = fmaf(w[7], R3[d], v); v = fmaf(w[8], p3, v);
        out[(size_t)(npair + r) * 128 + d] = f2bf(v);
        s += v; ss += v * v;
        __syncthreads();
    }
    red[t] = s; red[256 + t] = ss;
    __syncthreads();
    if (t < 128) {
        atomicAdd(&stats[6 * 128 + t], red[t] + red[t + 128]);
        atomicAdd(&stats[7 * 128 + t], red[256 + t] + red[256 + t + 128]);
    }
}

// ---------------- graph pooling (gid sorted), bf16 inputs ----------------

__global__ __launch_bounds__(256) void pool_kernel(const ushort* __restrict__ x2,
                                                   const ushort* __restrict__ x3,
                                                   const ushort* __restrict__ x4,
                                                   const int* __restrict__ gid,
                                                   float* __restrict__ hg) {
    int t = threadIdx.x;
    int d = t & 127, r = t >> 7;
    int n0 = blockIdx.x * 64;
    float a2 = 0.f, a3 = 0.f, a4 = 0.f;
    int g = gid[n0 + r];
    for (int it = 0; it < 32; ++it) {
        int n = n0 + it * 2 + r;
        int gn = gid[n];
        if (gn != g) {
            atomicAdd(&hg[g * 384 + d], a2);
            atomicAdd(&hg[g * 384 + 128 + d], a3);
            atomicAdd(&hg[g * 384 + 256 + d], a4);
            a2 = a3 = a4 = 0.f;
            g = gn;
        }
        size_t base = (size_t)n * 128 + d;
        a2 += bf2f(x2[base]); a3 += bf2f(x3[base]); a4 += bf2f(x4[base]);
    }
    atomicAdd(&hg[g * 384 + d], a2);
    atomicAdd(&hg[g * 384 + 128 + d], a3);
    atomicAdd(&hg[g * 384 + 256 + d], a4);
}

// ---------------- final classifier ----------------

__global__ __launch_bounds__(128) void final_kernel(const float* __restrict__ hg,
                                                    const float* __restrict__ w1,
                                                    const float* __restrict__ b1,
                                                    const float* __restrict__ w2,
                                                    const float* __restrict__ b2,
                                                    float* __restrict__ out) {
    __shared__ float hgs[16 * 384];
    __shared__ float tmp[16 * 128];
    int t = threadIdx.x;
    for (int idx = t; idx < 16 * 384; idx += 128) hgs[idx] = hg[idx];
    __syncthreads();
    for (int g = 0; g < 16; ++g) {
        float acc = b1[t];
        for (int k = 0; k < 384; k++) acc = fmaf(hgs[g * 384 + k], w1[t * 384 + k], acc);
        tmp[g * 128 + t] = acc;
    }
    __syncthreads();
    if (t < 80) {
        int g = t / 5, c = t % 5;
        float acc = b2[c];
        for (int j = 0; j < 128; j++) acc = fmaf(tmp[g * 128 + j], w2[c * 128 + j], acc);
        out[g * 5 + c] = acc;
    }
}

// ---------------- launch ----------------

extern "C" void kernel_launch(void* const* d_in, const int* in_sizes, int n_in,
                              void* d_out, int out_size, void* d_ws, size_t ws_size,
                              hipStream_t stream) {
    (void)in_sizes; (void)n_in; (void)out_size;

    const float* h        = (const float*)d_in[0];
    const float* edge_w   = (const float*)d_in[1];
    const int*   src      = (const int*)d_in[2];
    const int*   dst      = (const int*)d_in[3];
    const int*   node_gid = (const int*)d_in[4];
    const float* c1w = (const float*)d_in[6];
    const float* c1b = (const float*)d_in[7];
    const float* c2w = (const float*)d_in[8];
    const float* c2b = (const float*)d_in[9];
    const float* c3w = (const float*)d_in[10];
    const float* c3b = (const float*)d_in[11];
    const float* pw  = (const float*)d_in[12];
    const float* pb  = (const float*)d_in[13];
    const float* g11w = (const float*)d_in[14];
    const float* g11b = (const float*)d_in[15];
    const float* g12w = (const float*)d_in[16];
    const float* g12b = (const float*)d_in[17];
    const float* g13w = (const float*)d_in[18];
    const float* g13b = (const float*)d_in[19];
    const float* g2w = (const float*)d_in[20];
    const float* g2b = (const float*)d_in[21];
    const float* g3w = (const float*)d_in[22];
    const float* g3b = (const float*)d_in[23];
    const float* g4w = (const float*)d_in[24];
    const float* g4b = (const float*)d_in[25];
    const float* bng = (const float*)d_in[26];
    const float* bnb = (const float*)d_in[27];
    const float* cls1w = (const float*)d_in[28];
    const float* cls1b = (const float*)d_in[29];
    const float* cls2w = (const float*)d_in[30];
    const float* cls2b = (const float*)d_in[31];

    const size_t NW = (size_t)NN * 128;
    ushort* U1 = (ushort*)d_ws;
    ushort* U2 = U1 + NW;
    ushort* U3 = U2 + NW;
    ushort* U4 = U3 + NW;
    ushort* G  = U4 + NW;
    int2*   ecw = (int2*)(G + NW);           // E * 8B
    float*  stats = (float*)(ecw + EE);      // 8*128
    float*  scsh  = stats + 1024;            // 4*256
    ushort* wTb   = (ushort*)(scsh + 1024);  // 9*16384 bf16 frags (conv)
    ushort* wGb   = wTb + 9 * 16384;         // 6*16384 bf16 frags (gconv)
    float*  hg    = (float*)(wGb + 6 * 16384); // 16*384
    int*    rp    = (int*)(hg + 16 * 384);   // N+1
    int*    cur   = rp + (NN + 1);           // N
    int*    deg   = cur + NN;                // N
    int*    bsum  = deg + NN;                // 128
    int*    boff  = bsum + 128;              // 128
    size_t required = (size_t)((char*)(boff + 128) - (char*)d_ws);

    if (ws_size < required) {
        dbg_kernel<<<1, 128, 0, stream>>>((float*)d_out, (float)ws_size,
                                          (float)(ws_size >> 20));
        return;
    }

    hipMemsetAsync(deg, 0, (size_t)NN * 4, stream);
    hipMemsetAsync(stats, 0, 1024 * 4, stream);
    hipMemsetAsync(hg, 0, (size_t)16 * 384 * 4, stream);

    // CSR build
    hist_kernel<<<EE / 256, 256, 0, stream>>>(dst, deg);
    scanA_kernel<<<128, 1024, 0, stream>>>(deg, rp, bsum);
    scanB_kernel<<<1, 128, 0, stream>>>(bsum, boff);
    scanC_kernel<<<128, 1024, 0, stream>>>(rp, boff);
    hipMemcpyAsync(cur, rp, (size_t)NN * 4, hipMemcpyDeviceToDevice, stream);
    scatter_kernel<<<EE / 256, 256, 0, stream>>>(src, dst, edge_w, cur, ecw);

    // weight prep (bf16 fragment layouts)
    prepw_conv<<<576, 256, 0, stream>>>(c1w, c2w, c3w, wTb);
    prepw_g<<<384, 256, 0, stream>>>(g11w, g12w, g13w, g2w, g3w, g4w, wGb);

    // conv path: U1=t1, U2=t2, U3=t3 (bf16) + BN stats
    conv_kernel<<<NN / 64, 256, 0, stream>>>(h, wTb, c1b, c2b, c3b, U1, U2, U3, stats);
    bnfin_kernel<<<1, 128, 0, stream>>>(stats, bng, bnb, scsh, 0, 3);

    // gconvs: gather (BN affine fused) -> G, then MFMA GEMM
    gather_kernel<<<NN / 4, 256, 0, stream>>>(U1, rp, ecw, scsh + 0 * 256, G);
    gemm_kernel<<<NN / 64, 256, 0, stream>>>(G, wGb + 0 * 16384, g11b, U4);   // a1
    gather_kernel<<<NN / 4, 256, 0, stream>>>(U2, rp, ecw, scsh + 1 * 256, G);
    gemm_kernel<<<NN / 64, 256, 0, stream>>>(G, wGb + 1 * 16384, g12b, U1);   // a2
    gather_kernel<<<NN / 4, 256, 0, stream>>>(U3, rp, ecw, scsh + 2 * 256, G);
    gemm_kernel<<<NN / 64, 256, 0, stream>>>(G, wGb + 2 * 16384, g13b, U2);   // a3

    // press(a1,a2,a3) -> U3 (= ac_h1 pre-BN) + stats
    press_kernel<<<NN / 64, 256, 0, stream>>>(U4, U1, U2, pw, pb, U3, stats);
    bnfin_kernel<<<1, 128, 0, stream>>>(stats, bng, bnb, scsh, 3, 1);

    // chained gconvs: ac_h2 -> U4, ac_h3 -> U1, ac_h4 -> U2
    gather_kernel<<<NN / 4, 256, 0, stream>>>(U3, rp, ecw, scsh + 3 * 256, G);
    gemm_kernel<<<NN / 64, 256, 0, stream>>>(G, wGb + 3 * 16384, g2b, U4);
    gather_kernel<<<NN / 4, 256, 0, stream>>>(U4, rp, ecw, nullptr, G);
    gemm_kernel<<<NN / 64, 256, 0, stream>>>(G, wGb + 4 * 16384, g3b, U1);
    gather_kernel<<<NN / 4, 256, 0, stream>>>(U1, rp, ecw, nullptr, G);
    gemm_kernel<<<NN / 64, 256, 0, stream>>>(G, wGb + 5 * 16384, g4b, U2);

    // pooling + classifier
    pool_kernel<<<NN / 64, 256, 0, stream>>>(U4, U1, U2, node_gid, hg);
    final_kernel<<<1, 128, 0, stream>>>(hg, cls1w, cls1b, cls2w, cls2b, (float*)d_out);
}

// Round 5
// 1272.846 us; speedup vs baseline: 2.7731x; 1.2602x over previous
//
#include <hip/hip_runtime.h>
#include <hip/hip_bf16.h>

#define NN 131072
#define EE 2097152
#define EPSS 1e-5f

typedef float f32x4 __attribute__((ext_vector_type(4)));
typedef short s16x8 __attribute__((ext_vector_type(8)));

static __device__ __forceinline__ ushort f2bf(float f) {
    uint u = __float_as_uint(f);
    u += 0x7fffu + ((u >> 16) & 1u);
    return (ushort)(u >> 16);
}
static __device__ __forceinline__ float bf2f(ushort h) {
    return __uint_as_float(((uint)h) << 16);
}

// ---------------- debug: leak ws_size through d_out if workspace too small ----------------

__global__ void dbg_kernel(float* __restrict__ out, float a, float b) {
    int i = threadIdx.x;
    if (i < 80) out[i] = (i == 0) ? a : ((i == 1) ? b : 0.f);
}

// ---------------- CSR build ----------------

__global__ void hist_kernel(const int* __restrict__ dst, int* __restrict__ deg) {
    int e = blockIdx.x * 256 + threadIdx.x;
    if (e < EE) atomicAdd(&deg[dst[e]], 1);
}

__global__ __launch_bounds__(1024) void scanA_kernel(const int* __restrict__ deg,
                                                     int* __restrict__ rp,
                                                     int* __restrict__ bsum) {
    __shared__ int sh[1024];
    int t = threadIdx.x;
    int base = blockIdx.x * 1024;
    int v = deg[base + t];
    sh[t] = v;
    __syncthreads();
    for (int off = 1; off < 1024; off <<= 1) {
        int x = (t >= off) ? sh[t - off] : 0;
        __syncthreads();
        sh[t] += x;
        __syncthreads();
    }
    rp[base + t + 1] = sh[t];
    if (t == 1023) bsum[blockIdx.x] = sh[t];
}

__global__ __launch_bounds__(128) void scanB_kernel(int* __restrict__ bsum, int* __restrict__ boff) {
    __shared__ int sh[128];
    int t = threadIdx.x;
    int v = bsum[t];
    sh[t] = v;
    __syncthreads();
    for (int off = 1; off < 128; off <<= 1) {
        int x = (t >= off) ? sh[t - off] : 0;
        __syncthreads();
        sh[t] += x;
        __syncthreads();
    }
    boff[t] = sh[t] - v;  // exclusive
}

__global__ __launch_bounds__(1024) void scanC_kernel(int* __restrict__ rp, const int* __restrict__ boff) {
    int t = threadIdx.x;
    int b = blockIdx.x;
    rp[b * 1024 + t + 1] += boff[b];
    if (b == 0 && t == 0) rp[0] = 0;
}

__global__ void scatter_kernel(const int* __restrict__ src, const int* __restrict__ dst,
                               const float* __restrict__ ew, int* __restrict__ cur,
                               int2* __restrict__ ecw) {
    int e = blockIdx.x * 256 + threadIdx.x;
    if (e < EE) {
        int n = dst[e];
        int p = atomicAdd(&cur[n], 1);
        ecw[p] = make_int2(src[e], __float_as_int(ew[e]));
    }
}

// ---------------- weight prep: bf16 MFMA B-fragment layouts ----------------
// layout: [ck][kc(4)][ot(8)][lane(64)][j(8)], elem = W[i= kc*32+(lane>>4)*8+j][o= ot*16+(lane&15)]

__global__ void prepw_conv(const float* __restrict__ w1, const float* __restrict__ w2,
                           const float* __restrict__ w3, ushort* __restrict__ wTb) {
    int idx = blockIdx.x * 256 + threadIdx.x;
    if (idx >= 9 * 16384) return;
    int j = idx & 7;
    int lane = (idx >> 3) & 63;
    int ot = (idx >> 9) & 7;
    int kc = (idx >> 12) & 3;
    int ck = idx >> 14;            // c*3+k
    int k = ck % 3, c = ck / 3;
    int i = kc * 32 + (lane >> 4) * 8 + j;
    int o = ot * 16 + (lane & 15);
    const float* w = (c == 0) ? w1 : ((c == 1) ? w2 : w3);
    wTb[idx] = f2bf(w[o * 384 + i * 3 + k]);
}

__global__ void prepw_g(const float* __restrict__ w0, const float* __restrict__ w1,
                        const float* __restrict__ w2, const float* __restrict__ w3,
                        const float* __restrict__ w4, const float* __restrict__ w5,
                        ushort* __restrict__ wGb) {
    int idx = blockIdx.x * 256 + threadIdx.x;
    if (idx >= 6 * 16384) return;
    int j = idx & 7;
    int lane = (idx >> 3) & 63;
    int ot = (idx >> 9) & 7;
    int kc = (idx >> 12) & 3;
    int m = idx >> 14;
    int i = kc * 32 + (lane >> 4) * 8 + j;
    int o = ot * 16 + (lane & 15);
    const float* w = (m == 0) ? w0 : ((m == 1) ? w1 : ((m == 2) ? w2 :
                     ((m == 3) ? w3 : ((m == 4) ? w4 : w5))));
    wGb[idx] = f2bf(w[i * 128 + o]);
}

// ---------------- fused dilated convs via MFMA + combine + BN stats ----------------
// block = 64 nodes, 4 waves; wave wv owns output tiles ot={2wv,2wv+1} for ALL 64 nodes:
// each B-fragment feeds 4 MFMAs (row-group reuse), only 8 global B-loads per ck step.

__global__ __launch_bounds__(256) void conv_kernel(const float* __restrict__ h,
        const ushort* __restrict__ wTb,
        const float* __restrict__ b1, const float* __restrict__ b2, const float* __restrict__ b3,
        ushort* __restrict__ o1, ushort* __restrict__ o2, ushort* __restrict__ o3,
        float* __restrict__ stats) {
    __shared__ char smem[17920];
    __shared__ float red[768];
    int t = threadIdx.x;
    int n0 = blockIdx.x * 64;

    for (int idx = t; idx < 768; idx += 256) red[idx] = 0.f;

    for (int idx = t; idx < 70 * 32; idx += 256) {
        int row = idx >> 5, c4 = idx & 31;
        int gn = n0 - 3 + row;
        float4 v = make_float4(0.f, 0.f, 0.f, 0.f);
        if (gn >= 0 && gn < NN) v = *(const float4*)&h[(size_t)gn * 128 + c4 * 4];
        ushort4 pk;
        pk.x = f2bf(v.x); pk.y = f2bf(v.y); pk.z = f2bf(v.z); pk.w = f2bf(v.w);
        *(ushort4*)(smem + ((row * 256 + c4 * 8) ^ ((row & 7) << 4))) = pk;
    }
    __syncthreads();

    int wv = t >> 6, lane = t & 63;
    int fbase = lane & 15, grp = lane >> 4;
    int cbb = grp << 4;

    f32x4 acc[3][2][4];
#pragma unroll
    for (int c = 0; c < 3; c++)
#pragma unroll
        for (int o2 = 0; o2 < 2; o2++)
#pragma unroll
            for (int rg = 0; rg < 4; rg++) acc[c][o2][rg] = (f32x4){0.f, 0.f, 0.f, 0.f};

#pragma unroll
    for (int ck = 0; ck < 9; ck++) {
        const int c = ck / 3, k = ck % 3;
        const int shift = (c + 1) * (k - 1);
#pragma unroll
        for (int kc = 0; kc < 4; kc++) {
            s16x8 bA = *(const s16x8*)(wTb + (size_t)(((ck * 4 + kc) * 8 + wv * 2) * 512 + lane * 8));
            s16x8 bB = *(const s16x8*)(wTb + (size_t)(((ck * 4 + kc) * 8 + wv * 2 + 1) * 512 + lane * 8));
#pragma unroll
            for (int rg = 0; rg < 4; rg++) {
                int rr = rg * 16 + fbase + 3 + shift;
                s16x8 a = *(const s16x8*)(smem + ((rr * 256 + kc * 64 + cbb) ^ ((rr & 7) << 4)));
                acc[c][0][rg] = __builtin_amdgcn_mfma_f32_16x16x32_bf16(a, bA, acc[c][0][rg], 0, 0, 0);
                acc[c][1][rg] = __builtin_amdgcn_mfma_f32_16x16x32_bf16(a, bB, acc[c][1][rg], 0, 0, 0);
            }
        }
    }

    __syncthreads();   // done reading staged x; reuse smem for output transpose

#pragma unroll
    for (int p = 0; p < 3; p++) {
        const int pa = p, pbx = (p + 1) % 3;
        const float* Ba = (p == 0) ? b1 : ((p == 1) ? b2 : b3);
        const float* Bb = (p == 0) ? b2 : ((p == 1) ? b3 : b1);
        ushort* Op = (p == 0) ? o1 : ((p == 1) ? o2 : o3);
#pragma unroll
        for (int o2 = 0; o2 < 2; o2++) {
            int f = (wv * 2 + o2) * 16 + fbase;
            float bba = Ba[f], bbb = Bb[f];
            float s = 0.f, ss = 0.f;
#pragma unroll
            for (int rg = 0; rg < 4; rg++) {
#pragma unroll
                for (int q = 0; q < 4; q++) {
                    float ca = acc[pa][o2][rg][q] + bba;
                    float cb = acc[pbx][o2][rg][q] + bbb;
                    float tv = fmaxf(ca, 0.f) + cb;
                    int nl = rg * 16 + grp * 4 + q;
                    *(ushort*)(smem + ((nl * 256 + f * 2) ^ ((nl & 7) << 4))) = f2bf(tv);
                    s += tv; ss += tv * tv;
                }
            }
            s  += __shfl_xor(s, 16);  s  += __shfl_xor(s, 32);
            ss += __shfl_xor(ss, 16); ss += __shfl_xor(ss, 32);
            if (lane < 16) {
                atomicAdd(&red[(2 * p) * 128 + f], s);
                atomicAdd(&red[(2 * p + 1) * 128 + f], ss);
            }
        }
        __syncthreads();
        for (int idx = t; idx < 1024; idx += 256) {
            int row = idx >> 4, c16 = idx & 15;
            uint4 v = *(const uint4*)(smem + ((row * 256 + c16 * 16) ^ ((row & 7) << 4)));
            *(uint4*)&Op[(size_t)(n0 + row) * 128 + c16 * 8] = v;
        }
        __syncthreads();
    }

    if (t < 128) {
#pragma unroll
        for (int p6 = 0; p6 < 6; p6++)
            atomicAdd(&stats[p6 * 128 + t], red[p6 * 128 + t]);
    }
}

// ---------------- BN finalize ----------------

__global__ __launch_bounds__(128) void bnfin_kernel(const float* __restrict__ stats,
                                                    const float* __restrict__ g,
                                                    const float* __restrict__ b,
                                                    float* __restrict__ scsh, int q0, int nq) {
    int d = threadIdx.x;
    for (int q = q0; q < q0 + nq; ++q) {
        float s  = stats[(2 * q) * 128 + d];
        float ss = stats[(2 * q + 1) * 128 + d];
        float mu  = s * (1.f / NN);
        float var = ss * (1.f / NN) - mu * mu;
        float sc = g[d] / sqrtf(var + EPSS);
        float sh = b[d] - mu * sc;
        scsh[q * 256 + d] = sc;
        scsh[q * 256 + 128 + d] = sh;
    }
}

// ---------------- standalone CSR gather (+BN affine), one wave per node ----------------
// masked batches of 8 (no serial tail) + next-batch edge-record prefetch

__global__ __launch_bounds__(256) void gather_kernel(const ushort* __restrict__ xb,
        const int* __restrict__ rp, const int2* __restrict__ ecw,
        const float* __restrict__ scsh, ushort* __restrict__ G) {
    int t = threadIdx.x;
    int wid = blockIdx.x * 4 + (t >> 6);
    int lane = t & 63;
    uint laneoff = lane * 2;
    float scx = 1.f, scy = 1.f, shx = 0.f, shy = 0.f;
    if (scsh) {
        float2 sc = *(const float2*)&scsh[laneoff];
        float2 sh = *(const float2*)&scsh[128 + laneoff];
        scx = sc.x; scy = sc.y; shx = sh.x; shy = sh.y;
    }
    int beg = rp[wid], end = rp[wid + 1];
    int nb = (end - beg + 7) >> 3;
    float ax = 0.f, ay = 0.f, sw = 0.f;

    int2 ecb[8];
    if (nb > 0) {
#pragma unroll
        for (int q = 0; q < 8; q++) {
            int i = beg + q;
            int ic = (i < end) ? i : (end - 1);
            int2 v = ecw[ic];
            if (i >= end) v.y = 0;
            ecb[q] = v;
        }
    }
    for (int b = 0; b < nb; b++) {
        uint u[8];
#pragma unroll
        for (int q = 0; q < 8; q++)
            u[q] = *(const uint*)&xb[((uint)ecb[q].x << 7) + laneoff];

        int2 ecn[8];
        int e0n = beg + (b + 1) * 8;
#pragma unroll
        for (int q = 0; q < 8; q++) {
            int i = e0n + q;
            int ic = (i < end) ? i : (end - 1);
            int2 v = ecw[ic];
            if (i >= end) v.y = 0;
            ecn[q] = v;
        }
#pragma unroll
        for (int q = 0; q < 8; q++) {
            float w0 = __int_as_float(ecb[q].y);
            ax = fmaf(w0, __uint_as_float(u[q] << 16), ax);
            ay = fmaf(w0, __uint_as_float(u[q] & 0xffff0000u), ay);
            sw += w0;
        }
#pragma unroll
        for (int q = 0; q < 8; q++) ecb[q] = ecn[q];
    }

    if (scsh) {
        ax = fmaf(sw, shx, ax * scx);
        ay = fmaf(sw, shy, ay * scy);
    }
    uint pk = (uint)f2bf(ax) | ((uint)f2bf(ay) << 16);
    *(uint*)&G[(size_t)wid * 128 + laneoff] = pk;
}

// ---------------- MFMA GEMM: Y = relu(X @ W + b), bf16 in/out ----------------
// per-wave B-fragments preloaded into VGPRs once (no in-loop global loads)

__global__ __launch_bounds__(256) void gemm_kernel(const ushort* __restrict__ X,
        const ushort* __restrict__ wF, const float* __restrict__ bias,
        ushort* __restrict__ Y) {
    __shared__ char smem[16384];
    int t = threadIdx.x;
    int n0 = blockIdx.x * 64;
    int wv = t >> 6, lane = t & 63;

    s16x8 bfrag[4][2];
#pragma unroll
    for (int kc = 0; kc < 4; kc++)
#pragma unroll
        for (int o2 = 0; o2 < 2; o2++)
            bfrag[kc][o2] = *(const s16x8*)(wF + (size_t)((kc * 8 + wv * 2 + o2) * 512 + lane * 8));

    for (int idx = t; idx < 1024; idx += 256) {
        int row = idx >> 4, c16 = idx & 15;
        uint4 v = *(const uint4*)&X[(size_t)(n0 + row) * 128 + c16 * 8];
        *(uint4*)(smem + ((row * 256 + c16 * 16) ^ ((row & 7) << 4))) = v;
    }
    __syncthreads();

    int fbase = lane & 15, grp = lane >> 4, cbb = grp << 4;
    f32x4 acc[2][4];
#pragma unroll
    for (int o2 = 0; o2 < 2; o2++)
#pragma unroll
        for (int rg = 0; rg < 4; rg++) acc[o2][rg] = (f32x4){0.f, 0.f, 0.f, 0.f};

#pragma unroll
    for (int kc = 0; kc < 4; kc++) {
#pragma unroll
        for (int rg = 0; rg < 4; rg++) {
            int rr = rg * 16 + fbase;
            s16x8 a = *(const s16x8*)(smem + ((rr * 256 + kc * 64 + cbb) ^ ((rr & 7) << 4)));
            acc[0][rg] = __builtin_amdgcn_mfma_f32_16x16x32_bf16(a, bfrag[kc][0], acc[0][rg], 0, 0, 0);
            acc[1][rg] = __builtin_amdgcn_mfma_f32_16x16x32_bf16(a, bfrag[kc][1], acc[1][rg], 0, 0, 0);
        }
    }

    __syncthreads();
#pragma unroll
    for (int o2 = 0; o2 < 2; o2++) {
        int f = (wv * 2 + o2) * 16 + fbase;
        float bb = bias[f];
#pragma unroll
        for (int rg = 0; rg < 4; rg++)
#pragma unroll
            for (int q = 0; q < 4; q++) {
                float y = fmaxf(acc[o2][rg][q] + bb, 0.f);
                int nl = rg * 16 + grp * 4 + q;
                *(ushort*)(smem + ((nl * 256 + f * 2) ^ ((nl & 7) << 4))) = f2bf(y);
            }
    }
    __syncthreads();
    for (int idx = t; idx < 1024; idx += 256) {
        int row = idx >> 4, c16 = idx & 15;
        uint4 v = *(const uint4*)(smem + ((row * 256 + c16 * 16) ^ ((row & 7) << 4)));
        *(uint4*)&Y[(size_t)(n0 + row) * 128 + c16 * 8] = v;
    }
}

// ---------------- press (1x3x3 conv over [N,3,D]) + BN stats (bf16 I/O) ----------------

__global__ __launch_bounds__(256) void press_kernel(const ushort* __restrict__ a1,
                                                    const ushort* __restrict__ a2,
                                                    const ushort* __restrict__ a3,
                                                    const float* __restrict__ pw,
                                                    const float* __restrict__ pb_,
                                                    ushort* __restrict__ out,
                                                    float* __restrict__ stats) {
    __shared__ float rows[6 * 128];
    __shared__ float red[512];
    int t = threadIdx.x;
    int d = t & 127, r = t >> 7;
    int n0 = blockIdx.x * 64;
    float w[9];
#pragma unroll
    for (int q = 0; q < 9; q++) w[q] = pw[q];
    float pb = pb_[0];

    float s = 0.f, ss = 0.f;
    for (int it = 0; it < 32; ++it) {
        int npair = n0 + it * 2;
#pragma unroll
        for (int q = 0; q < 3; q++) {
            int idx = q * 256 + t;
            int row = idx >> 7, col = idx & 127;
            int c = row >> 1, rr = row & 1;
            size_t off = (size_t)(npair + rr) * 128 + col;
            ushort v = (c == 0) ? a1[off] : ((c == 1) ? a2[off] : a3[off]);
            rows[row * 128 + col] = bf2f(v);
        }
        __syncthreads();
        const float* R1 = &rows[(0 + r) * 128];
        const float* R2 = &rows[(2 + r) * 128];
        const float* R3 = &rows[(4 + r) * 128];
        float m1 = (d > 0) ? R1[d - 1] : 0.f;
        float m2 = (d > 0) ? R2[d - 1] : 0.f;
        float m3 = (d > 0) ? R3[d - 1] : 0.f;
        float p1 = (d < 127) ? R1[d + 1] : 0.f;
        float p2 = (d < 127) ? R2[d + 1] : 0.f;
        float p3 = (d < 127) ? R3[d + 1] : 0.f;
        float v = pb;
        v = fmaf(w[0], m1, v); v = fmaf(w[1], R1[d], v); v = fmaf(w[2], p1, v);
        v = fmaf(w[3], m2, v); v = fmaf(w[4], R2[d], v); v = fmaf(w[5], p2, v);
        v = fmaf(w[6], m3, v); v = fmaf(w[7], R3[d], v); v = fmaf(w[8], p3, v);
        out[(size_t)(npair + r) * 128 + d] = f2bf(v);
        s += v; ss += v * v;
        __syncthreads();
    }
    red[t] = s; red[256 + t] = ss;
    __syncthreads();
    if (t < 128) {
        atomicAdd(&stats[6 * 128 + t], red[t] + red[t + 128]);
        atomicAdd(&stats[7 * 128 + t], red[256 + t] + red[256 + t + 128]);
    }
}

// ---------------- graph pooling (gid sorted), bf16 inputs ----------------

__global__ __launch_bounds__(256) void pool_kernel(const ushort* __restrict__ x2,
                                                   const ushort* __restrict__ x3,
                                                   const ushort* __restrict__ x4,
                                                   const int* __restrict__ gid,
                                                   float* __restrict__ hg) {
    int t = threadIdx.x;
    int d = t & 127, r = t >> 7;
    int n0 = blockIdx.x * 64;
    float a2 = 0.f, a3 = 0.f, a4 = 0.f;
    int g = gid[n0 + r];
    for (int it = 0; it < 32; ++it) {
        int n = n0 + it * 2 + r;
        int gn = gid[n];
        if (gn != g) {
            atomicAdd(&hg[g * 384 + d], a2);
            atomicAdd(&hg[g * 384 + 128 + d], a3);
            atomicAdd(&hg[g * 384 + 256 + d], a4);
            a2 = a3 = a4 = 0.f;
            g = gn;
        }
        size_t base = (size_t)n * 128 + d;
        a2 += bf2f(x2[base]); a3 += bf2f(x3[base]); a4 += bf2f(x4[base]);
    }
    atomicAdd(&hg[g * 384 + d], a2);
    atomicAdd(&hg[g * 384 + 128 + d], a3);
    atomicAdd(&hg[g * 384 + 256 + d], a4);
}

// ---------------- final classifier ----------------

__global__ __launch_bounds__(128) void final_kernel(const float* __restrict__ hg,
                                                    const float* __restrict__ w1,
                                                    const float* __restrict__ b1,
                                                    const float* __restrict__ w2,
                                                    const float* __restrict__ b2,
                                                    float* __restrict__ out) {
    __shared__ float hgs[16 * 384];
    __shared__ float tmp[16 * 128];
    int t = threadIdx.x;
    for (int idx = t; idx < 16 * 384; idx += 128) hgs[idx] = hg[idx];
    __syncthreads();
    for (int g = 0; g < 16; ++g) {
        float acc = b1[t];
        for (int k = 0; k < 384; k++) acc = fmaf(hgs[g * 384 + k], w1[t * 384 + k], acc);
        tmp[g * 128 + t] = acc;
    }
    __syncthreads();
    if (t < 80) {
        int g = t / 5, c = t % 5;
        float acc = b2[c];
        for (int j = 0; j < 128; j++) acc = fmaf(tmp[g * 128 + j], w2[c * 128 + j], acc);
        out[g * 5 + c] = acc;
    }
}

// ---------------- launch ----------------

extern "C" void kernel_launch(void* const* d_in, const int* in_sizes, int n_in,
                              void* d_out, int out_size, void* d_ws, size_t ws_size,
                              hipStream_t stream) {
    (void)in_sizes; (void)n_in; (void)out_size;

    const float* h        = (const float*)d_in[0];
    const float* edge_w   = (const float*)d_in[1];
    const int*   src      = (const int*)d_in[2];
    const int*   dst      = (const int*)d_in[3];
    const int*   node_gid = (const int*)d_in[4];
    const float* c1w = (const float*)d_in[6];
    const float* c1b = (const float*)d_in[7];
    const float* c2w = (const float*)d_in[8];
    const float* c2b = (const float*)d_in[9];
    const float* c3w = (const float*)d_in[10];
    const float* c3b = (const float*)d_in[11];
    const float* pw  = (const float*)d_in[12];
    const float* pb  = (const float*)d_in[13];
    const float* g11w = (const float*)d_in[14];
    const float* g11b = (const float*)d_in[15];
    const float* g12w = (const float*)d_in[16];
    const float* g12b = (const float*)d_in[17];
    const float* g13w = (const float*)d_in[18];
    const float* g13b = (const float*)d_in[19];
    const float* g2w = (const float*)d_in[20];
    const float* g2b = (const float*)d_in[21];
    const float* g3w = (const float*)d_in[22];
    const float* g3b = (const float*)d_in[23];
    const float* g4w = (const float*)d_in[24];
    const float* g4b = (const float*)d_in[25];
    const float* bng = (const float*)d_in[26];
    const float* bnb = (const float*)d_in[27];
    const float* cls1w = (const float*)d_in[28];
    const float* cls1b = (const float*)d_in[29];
    const float* cls2w = (const float*)d_in[30];
    const float* cls2b = (const float*)d_in[31];

    const size_t NW = (size_t)NN * 128;
    ushort* U1 = (ushort*)d_ws;
    ushort* U2 = U1 + NW;
    ushort* U3 = U2 + NW;
    ushort* U4 = U3 + NW;
    ushort* G  = U4 + NW;
    int2*   ecw = (int2*)(G + NW);           // E * 8B
    float*  stats = (float*)(ecw + EE);      // 8*128
    float*  scsh  = stats + 1024;            // 4*256
    ushort* wTb   = (ushort*)(scsh + 1024);  // 9*16384 bf16 frags (conv)
    ushort* wGb   = wTb + 9 * 16384;         // 6*16384 bf16 frags (gconv)
    float*  hg    = (float*)(wGb + 6 * 16384); // 16*384
    int*    rp    = (int*)(hg + 16 * 384);   // N+1
    int*    cur   = rp + (NN + 1);           // N
    int*    deg   = cur + NN;                // N
    int*    bsum  = deg + NN;                // 128
    int*    boff  = bsum + 128;              // 128
    size_t required = (size_t)((char*)(boff + 128) - (char*)d_ws);

    if (ws_size < required) {
        dbg_kernel<<<1, 128, 0, stream>>>((float*)d_out, (float)ws_size,
                                          (float)(ws_size >> 20));
        return;
    }

    hipMemsetAsync(deg, 0, (size_t)NN * 4, stream);
    hipMemsetAsync(stats, 0, 1024 * 4, stream);
    hipMemsetAsync(hg, 0, (size_t)16 * 384 * 4, stream);

    // CSR build
    hist_kernel<<<EE / 256, 256, 0, stream>>>(dst, deg);
    scanA_kernel<<<128, 1024, 0, stream>>>(deg, rp, bsum);
    scanB_kernel<<<1, 128, 0, stream>>>(bsum, boff);
    scanC_kernel<<<128, 1024, 0, stream>>>(rp, boff);
    hipMemcpyAsync(cur, rp, (size_t)NN * 4, hipMemcpyDeviceToDevice, stream);
    scatter_kernel<<<EE / 256, 256, 0, stream>>>(src, dst, edge_w, cur, ecw);

    // weight prep (bf16 fragment layouts)
    prepw_conv<<<576, 256, 0, stream>>>(c1w, c2w, c3w, wTb);
    prepw_g<<<384, 256, 0, stream>>>(g11w, g12w, g13w, g2w, g3w, g4w, wGb);

    // conv path: U1=t1, U2=t2, U3=t3 (bf16) + BN stats
    conv_kernel<<<NN / 64, 256, 0, stream>>>(h, wTb, c1b, c2b, c3b, U1, U2, U3, stats);
    bnfin_kernel<<<1, 128, 0, stream>>>(stats, bng, bnb, scsh, 0, 3);

    // gconvs: gather (BN affine fused) -> G, then MFMA GEMM
    gather_kernel<<<NN / 4, 256, 0, stream>>>(U1, rp, ecw, scsh + 0 * 256, G);
    gemm_kernel<<<NN / 64, 256, 0, stream>>>(G, wGb + 0 * 16384, g11b, U4);   // a1
    gather_kernel<<<NN / 4, 256, 0, stream>>>(U2, rp, ecw, scsh + 1 * 256, G);
    gemm_kernel<<<NN / 64, 256, 0, stream>>>(G, wGb + 1 * 16384, g12b, U1);   // a2
    gather_kernel<<<NN / 4, 256, 0, stream>>>(U3, rp, ecw, scsh + 2 * 256, G);
    gemm_kernel<<<NN / 64, 256, 0, stream>>>(G, wGb + 2 * 16384, g13b, U2);   // a3

    // press(a1,a2,a3) -> U3 (= ac_h1 pre-BN) + stats
    press_kernel<<<NN / 64, 256, 0, stream>>>(U4, U1, U2, pw, pb, U3, stats);
    bnfin_kernel<<<1, 128, 0, stream>>>(stats, bng, bnb, scsh, 3, 1);

    // chained gconvs: ac_h2 -> U4, ac_h3 -> U1, ac_h4 -> U2
    gather_kernel<<<NN / 4, 256, 0, stream>>>(U3, rp, ecw, scsh + 3 * 256, G);
    gemm_kernel<<<NN / 64, 256, 0, stream>>>(G, wGb + 3 * 16384, g2b, U4);
    gather_kernel<<<NN / 4, 256, 0, stream>>>(U4, rp, ecw, nullptr, G);
    gemm_kernel<<<NN / 64, 256, 0, stream>>>(G, wGb + 4 * 16384, g3b, U1);
    gather_kernel<<<NN / 4, 256, 0, stream>>>(U1, rp, ecw, nullptr, G);
    gemm_kernel<<<NN / 64, 256, 0, stream>>>(G, wGb + 5 * 16384, g4b, U2);

    // pooling + classifier
    pool_kernel<<<NN / 64, 256, 0, stream>>>(U4, U1, U2, node_gid, hg);
    final_kernel<<<1, 128, 0, stream>>>(hg, cls1w, cls1b, cls2w, cls2b, (float*)d_out);
}